// Round 1
// baseline (1417.947 us; speedup 1.0000x reference)
//
#include <hip/hip_runtime.h>
#include <hip/hip_bf16.h>
#include <math.h>

#define B_   16
#define T_   576
#define NH_  12

// ---------------------------------------------------------------------------
// Generic fp32 SGEMM: C[M,N] = A[M,K] @ W[K,N] (+ bias), row-major.
// 128x128 tile per 256-thread block, 8x8 per thread, K-tile = 16.
// Requires N % 128 == 0, K % 16 == 0; M guarded.
// ---------------------------------------------------------------------------
template<bool HAS_BIAS>
__global__ __launch_bounds__(256)
void gemm128(const float* __restrict__ A, const float* __restrict__ W,
             const float* __restrict__ bias, float* __restrict__ C,
             int M, int N, int K) {
    __shared__ float As[16][132];   // [k][m], padded (132*4=528B, 16B-aligned rows)
    __shared__ float Bs[16][132];   // [k][n]
    const int tid = threadIdx.x;
    const int tx = tid & 15, ty = tid >> 4;
    const int m0 = blockIdx.y * 128;
    const int n0 = blockIdx.x * 128;
    const int arow = tid >> 1;            // 0..127
    const int akq  = (tid & 1) * 8;       // 0 or 8
    const int bkk  = tid >> 4;            // 0..15
    const int bc8  = (tid & 15) * 8;      // 0..120

    float acc[8][8];
#pragma unroll
    for (int i = 0; i < 8; ++i)
#pragma unroll
        for (int j = 0; j < 8; ++j) acc[i][j] = 0.f;

    for (int k0 = 0; k0 < K; k0 += 16) {
        float4 a0 = make_float4(0.f,0.f,0.f,0.f), a1 = make_float4(0.f,0.f,0.f,0.f);
        const int row = m0 + arow;
        if (row < M) {
            const float* ap = A + (size_t)row * K + k0 + akq;
            a0 = *(const float4*)ap;
            a1 = *(const float4*)(ap + 4);
        }
        const float* wp = W + (size_t)(k0 + bkk) * N + n0 + bc8;
        const float4 b0 = *(const float4*)wp;
        const float4 b1 = *(const float4*)(wp + 4);
        __syncthreads();   // previous iter's LDS reads complete before overwrite
        As[akq+0][arow] = a0.x; As[akq+1][arow] = a0.y;
        As[akq+2][arow] = a0.z; As[akq+3][arow] = a0.w;
        As[akq+4][arow] = a1.x; As[akq+5][arow] = a1.y;
        As[akq+6][arow] = a1.z; As[akq+7][arow] = a1.w;
        *(float4*)&Bs[bkk][bc8]   = b0;
        *(float4*)&Bs[bkk][bc8+4] = b1;
        __syncthreads();
#pragma unroll
        for (int kk = 0; kk < 16; ++kk) {
            const float4 a_0 = *(const float4*)&As[kk][ty*8];
            const float4 a_1 = *(const float4*)&As[kk][ty*8+4];
            const float4 b_0 = *(const float4*)&Bs[kk][tx*8];
            const float4 b_1 = *(const float4*)&Bs[kk][tx*8+4];
            const float av[8] = {a_0.x,a_0.y,a_0.z,a_0.w,a_1.x,a_1.y,a_1.z,a_1.w};
            const float bv[8] = {b_0.x,b_0.y,b_0.z,b_0.w,b_1.x,b_1.y,b_1.z,b_1.w};
#pragma unroll
            for (int i = 0; i < 8; ++i)
#pragma unroll
                for (int j = 0; j < 8; ++j)
                    acc[i][j] = fmaf(av[i], bv[j], acc[i][j]);
        }
    }
#pragma unroll
    for (int i = 0; i < 8; ++i) {
        const int row = m0 + ty*8 + i;
        if (row < M) {
            float* cp = C + (size_t)row * N + n0 + tx*8;
            float4 o0, o1;
            o0.x = acc[i][0]; o0.y = acc[i][1]; o0.z = acc[i][2]; o0.w = acc[i][3];
            o1.x = acc[i][4]; o1.y = acc[i][5]; o1.z = acc[i][6]; o1.w = acc[i][7];
            if (HAS_BIAS) {
                const float* bp = bias + n0 + tx*8;
                o0.x += bp[0]; o0.y += bp[1]; o0.z += bp[2]; o0.w += bp[3];
                o1.x += bp[4]; o1.y += bp[5]; o1.z += bp[6]; o1.w += bp[7];
            }
            *(float4*)cp     = o0;
            *(float4*)(cp+4) = o1;
        }
    }
}

// ---------------------------------------------------------------------------
// 2x2 mean pool: lat (B,24,24,256) -> lp2 (B,12,12,256)
// ---------------------------------------------------------------------------
__global__ __launch_bounds__(256)
void pool2_kernel(const float* __restrict__ lat, float* __restrict__ lp2) {
    const int c = threadIdx.x;
    const int idx = blockIdx.x;            // b*144 + gh*12 + gw
    const int b = idx / 144;
    const int g = idx - b*144;
    const int gh = g / 12, gw = g - gh*12;
    const float* base = lat + (((size_t)(b*24 + gh*2))*24 + gw*2)*256 + c;
    const float s = base[0] + base[256] + base[24*256] + base[24*256 + 256];
    lp2[(size_t)idx*256 + c] = s * 0.25f;
}

// 2x2 mean pool of lp2: (B,12,12,256) -> lp4 (B,6,6,256)  (== 4x4 mean of lat)
__global__ __launch_bounds__(256)
void pool4_kernel(const float* __restrict__ lp2, float* __restrict__ lp4) {
    const int c = threadIdx.x;
    const int idx = blockIdx.x;            // b*36 + gh*6 + gw
    const int b = idx / 36;
    const int g = idx - b*36;
    const int gh = g / 6, gw = g - gh*6;
    const float* base = lp2 + (((size_t)(b*12 + gh*2))*12 + gw*2)*256 + c;
    const float s = base[0] + base[256] + base[12*256] + base[12*256 + 256];
    lp4[(size_t)idx*256 + c] = s * 0.25f;
}

// ---------------------------------------------------------------------------
// Fused attention for one scale, flash-style online softmax.
// Grid: (T/32, NH, B). Block: 256 threads = 32 q-rows x 8 dim-groups.
// Each thread owns 8 output dims of one q-row.
// CTX accumulated as += (1/3)*softmax(QK^T*s + bias)@V  (WRITE: first scale).
// ---------------------------------------------------------------------------
template<int S, int KS, int GW, bool WRITE>
__global__ __launch_bounds__(256)
void attn_kernel(const float* __restrict__ Q, const float* __restrict__ Km,
                 const float* __restrict__ Vm, const float* __restrict__ TBL,
                 float* __restrict__ CTX) {
    constexpr int TW = 2*GW - 1;
    __shared__ float qs[32][68];
    __shared__ float ks[32][68];
    __shared__ float vs[32][68];
    __shared__ float ps[32][32];
    const int tid  = threadIdx.x;
    const int r    = tid >> 3;      // q-row in tile (0..31)
    const int dsub = tid & 7;       // dim group (8 floats)
    const int qt0  = blockIdx.x * 32;
    const int h    = blockIdx.y;
    const int b    = blockIdx.z;
    const int qg   = qt0 + r;
    const int qh   = qg / 24;
    const int qw   = qg - qh*24;
    {
        const float* qp = Q + ((size_t)(b*T_ + qg))*768 + h*64 + dsub*8;
        *(float4*)&qs[r][dsub*8]   = *(const float4*)qp;
        *(float4*)&qs[r][dsub*8+4] = *(const float4*)(qp+4);
    }
    const float* tblh = TBL + (size_t)h * (47 * TW);
    float acc[8];
#pragma unroll
    for (int i = 0; i < 8; ++i) acc[i] = 0.f;
    float mrow = -INFINITY, lrow = 0.f;

    for (int kt0 = 0; kt0 < KS; kt0 += 32) {
        __syncthreads();   // previous iter's PV reads of vs done
        {
            const int key = kt0 + r;
            if (key < KS) {
                const float* kp = Km + ((size_t)(b*KS + key))*768 + h*64 + dsub*8;
                *(float4*)&ks[r][dsub*8]   = *(const float4*)kp;
                *(float4*)&ks[r][dsub*8+4] = *(const float4*)(kp+4);
                const float* vp = Vm + ((size_t)(b*KS + key))*768 + h*64 + dsub*8;
                *(float4*)&vs[r][dsub*8]   = *(const float4*)vp;
                *(float4*)&vs[r][dsub*8+4] = *(const float4*)(vp+4);
            }
        }
        __syncthreads();
        // scores: this thread computes keys c = dsub + 8j, j=0..3 for row r
        float sc[4] = {0.f, 0.f, 0.f, 0.f};
#pragma unroll
        for (int d4 = 0; d4 < 16; ++d4) {
            const float4 a = *(const float4*)&qs[r][d4*4];
#pragma unroll
            for (int j = 0; j < 4; ++j) {
                const float4 kv = *(const float4*)&ks[dsub + 8*j][d4*4];
                sc[j] = fmaf(a.x, kv.x, sc[j]);
                sc[j] = fmaf(a.y, kv.y, sc[j]);
                sc[j] = fmaf(a.z, kv.z, sc[j]);
                sc[j] = fmaf(a.w, kv.w, sc[j]);
            }
        }
#pragma unroll
        for (int j = 0; j < 4; ++j) {
            const int c  = dsub + 8*j;
            const int kg = kt0 + c;
            if (kg < KS) {
                const int khi = kg / GW;
                const int kwi = kg - khi*GW;
                int rel_h, rel_w;
                if (S == 1) {
                    rel_h = qh - khi + 23;
                    rel_w = qw - kwi + (GW - 1);
                } else {
                    // trunc-toward-zero of (q - (k*S + (S-1)/2)) matches .astype(int64)
                    rel_h = (int)((float)qh - ((float)(khi*S) + 0.5f*(S-1))) + 23;
                    rel_w = (int)((float)qw - ((float)(kwi*S) + 0.5f*(S-1))) + (GW - 1);
                }
                sc[j] = fmaf(sc[j], 0.125f, tblh[rel_h*TW + rel_w]);  // flat-index gather (matches ref)
            } else {
                sc[j] = -INFINITY;
            }
        }
        // row-wide max/sum across the 8 lanes sharing this row (same wave)
        float tmax = fmaxf(fmaxf(sc[0], sc[1]), fmaxf(sc[2], sc[3]));
        tmax = fmaxf(tmax, __shfl_xor(tmax, 1));
        tmax = fmaxf(tmax, __shfl_xor(tmax, 2));
        tmax = fmaxf(tmax, __shfl_xor(tmax, 4));
        const float newm   = fmaxf(mrow, tmax);
        const float factor = __expf(mrow - newm);   // 0 on first tile
        float tsum = 0.f;
#pragma unroll
        for (int j = 0; j < 4; ++j) {
            const float p = __expf(sc[j] - newm);   // 0 for masked keys
            ps[r][dsub + 8*j] = p;
            tsum += p;
        }
        tsum += __shfl_xor(tsum, 1);
        tsum += __shfl_xor(tsum, 2);
        tsum += __shfl_xor(tsum, 4);
        lrow = lrow * factor + tsum;
        mrow = newm;
#pragma unroll
        for (int i = 0; i < 8; ++i) acc[i] *= factor;
        // PV: ps[r][*] written/read by the same wave -> no barrier needed
#pragma unroll 8
        for (int c = 0; c < 32; ++c) {
            const float p = ps[r][c];
            const float4 v0 = *(const float4*)&vs[c][dsub*8];
            const float4 v1 = *(const float4*)&vs[c][dsub*8+4];
            acc[0] = fmaf(p, v0.x, acc[0]);
            acc[1] = fmaf(p, v0.y, acc[1]);
            acc[2] = fmaf(p, v0.z, acc[2]);
            acc[3] = fmaf(p, v0.w, acc[3]);
            acc[4] = fmaf(p, v1.x, acc[4]);
            acc[5] = fmaf(p, v1.y, acc[5]);
            acc[6] = fmaf(p, v1.z, acc[6]);
            acc[7] = fmaf(p, v1.w, acc[7]);
        }
    }
    const float invl = 1.0f / (3.0f * lrow);
    float* cp = CTX + ((size_t)(b*T_ + qg))*768 + h*64 + dsub*8;
    if (WRITE) {
        float4 o0, o1;
        o0.x = acc[0]*invl; o0.y = acc[1]*invl; o0.z = acc[2]*invl; o0.w = acc[3]*invl;
        o1.x = acc[4]*invl; o1.y = acc[5]*invl; o1.z = acc[6]*invl; o1.w = acc[7]*invl;
        *(float4*)cp     = o0;
        *(float4*)(cp+4) = o1;
    } else {
        float4 o0 = *(const float4*)cp;
        float4 o1 = *(const float4*)(cp+4);
        o0.x += acc[0]*invl; o0.y += acc[1]*invl; o0.z += acc[2]*invl; o0.w += acc[3]*invl;
        o1.x += acc[4]*invl; o1.y += acc[5]*invl; o1.z += acc[6]*invl; o1.w += acc[7]*invl;
        *(float4*)cp     = o0;
        *(float4*)(cp+4) = o1;
    }
}

// ---------------------------------------------------------------------------
extern "C" void kernel_launch(void* const* d_in, const int* in_sizes, int n_in,
                              void* d_out, int out_size, void* d_ws, size_t ws_size,
                              hipStream_t stream) {
    const float* x    = (const float*)d_in[0];
    const float* wq   = (const float*)d_in[1];
    const float* wdkv = (const float*)d_in[2];
    const float* wuk1 = (const float*)d_in[3];
    const float* wuk2 = (const float*)d_in[4];
    const float* wuk4 = (const float*)d_in[5];
    const float* wuv1 = (const float*)d_in[6];
    const float* wuv2 = (const float*)d_in[7];
    const float* wuv4 = (const float*)d_in[8];
    const float* wout = (const float*)d_in[9];
    const float* bout = (const float*)d_in[10];
    const float* tbl1 = (const float*)d_in[11];
    const float* tbl2 = (const float*)d_in[12];
    const float* tbl4 = (const float*)d_in[13];

    float* ws  = (float*)d_ws;
    float* qb  = ws;                  // 16*576*768  = 7077888
    float* lat = qb  + 7077888;       // 16*576*256  = 2359296
    float* lp2 = lat + 2359296;       // 16*144*256  = 589824
    float* lp4 = lp2 + 589824;        // 16*36*256   = 147456
    float* k1  = lp4 + 147456;        // 16*576*768  = 7077888
    float* v1  = k1  + 7077888;
    float* k2  = v1  + 7077888;       // 16*144*768  = 1769472
    float* v2  = k2  + 1769472;
    float* k4  = v2  + 1769472;       // 16*36*768   = 442368
    float* v4  = k4  + 442368;
    float* ctx = v4  + 442368;        // 7077888
    float* outp = (float*)d_out;

    // q and latent projections
    gemm128<false><<<dim3(6, 72), 256, 0, stream>>>(x, wq,   nullptr, qb,  9216, 768, 768);
    gemm128<false><<<dim3(2, 72), 256, 0, stream>>>(x, wdkv, nullptr, lat, 9216, 256, 768);
    // pooling
    pool2_kernel<<<16*144, 256, 0, stream>>>(lat, lp2);
    pool4_kernel<<<16*36,  256, 0, stream>>>(lp2, lp4);
    // K/V up-projections per scale
    gemm128<false><<<dim3(6, 72), 256, 0, stream>>>(lat, wuk1, nullptr, k1, 9216, 768, 256);
    gemm128<false><<<dim3(6, 72), 256, 0, stream>>>(lat, wuv1, nullptr, v1, 9216, 768, 256);
    gemm128<false><<<dim3(6, 18), 256, 0, stream>>>(lp2, wuk2, nullptr, k2, 2304, 768, 256);
    gemm128<false><<<dim3(6, 18), 256, 0, stream>>>(lp2, wuv2, nullptr, v2, 2304, 768, 256);
    gemm128<false><<<dim3(6, 5),  256, 0, stream>>>(lp4, wuk4, nullptr, k4,  576, 768, 256);
    gemm128<false><<<dim3(6, 5),  256, 0, stream>>>(lp4, wuv4, nullptr, v4,  576, 768, 256);
    // fused attention, accumulating (1/3 each) into ctx
    attn_kernel<1, 576, 24, true ><<<dim3(18, NH_, B_), 256, 0, stream>>>(qb, k1, v1, tbl1, ctx);
    attn_kernel<2, 144, 12, false><<<dim3(18, NH_, B_), 256, 0, stream>>>(qb, k2, v2, tbl2, ctx);
    attn_kernel<4,  36,  6, false><<<dim3(18, NH_, B_), 256, 0, stream>>>(qb, k4, v4, tbl4, ctx);
    // output projection + bias
    gemm128<true ><<<dim3(6, 72), 256, 0, stream>>>(ctx, wout, bout, outp, 9216, 768, 768);
}

// Round 2
// 1063.783 us; speedup vs baseline: 1.3329x; 1.3329x over previous
//
#include <hip/hip_runtime.h>
#include <hip/hip_bf16.h>
#include <math.h>

#define B_   16
#define T_   576
#define NH_  12

typedef unsigned short u16;
typedef __attribute__((ext_vector_type(8))) short bf16x8;
typedef __attribute__((ext_vector_type(4))) float f32x4;

// ---------------------------------------------------------------------------
// bf16 split helpers (hi + lo bf16 ~= 16 mantissa bits of fp32)
// ---------------------------------------------------------------------------
__device__ __forceinline__ float bf2f(u16 u) {
    union { unsigned int i; float f; } x; x.i = ((unsigned int)u) << 16; return x.f;
}
__device__ __forceinline__ u16 f2bf(float f) {   // round-to-nearest-even
    union { float f; unsigned int i; } x; x.f = f;
    unsigned int r = x.i + 0x7fffu + ((x.i >> 16) & 1u);
    return (u16)(r >> 16);
}
__device__ __forceinline__ void splitf(float v, u16& h, u16& l) {
    h = f2bf(v);
    l = f2bf(v - bf2f(h));
}

__device__ __forceinline__ void gld_lds16(const u16* g, u16* l) {
    __builtin_amdgcn_global_load_lds(
        (const __attribute__((address_space(1))) unsigned int*)g,
        (__attribute__((address_space(3))) unsigned int*)l, 16, 0, 0);
}

// ---------------------------------------------------------------------------
// convert fp32 -> (hi, lo) bf16
// ---------------------------------------------------------------------------
__global__ __launch_bounds__(256)
void convert_split(const float* __restrict__ in, u16* __restrict__ h,
                   u16* __restrict__ l, int n) {
    const int i4 = (blockIdx.x * 256 + threadIdx.x) * 4;
    if (i4 >= n) return;
    const float4 v = *(const float4*)&in[i4];
    u16 h0,h1,h2,h3, l0,l1,l2,l3;
    splitf(v.x,h0,l0); splitf(v.y,h1,l1); splitf(v.z,h2,l2); splitf(v.w,h3,l3);
    *(ushort4*)&h[i4] = make_ushort4(h0,h1,h2,h3);
    *(ushort4*)&l[i4] = make_ushort4(l0,l1,l2,l3);
}

// ---------------------------------------------------------------------------
// W[K][N] fp32 -> Wt_h[N][K], Wt_l[N][K] bf16 (transpose + split)
// grid (N/32, K/32), block 256
// ---------------------------------------------------------------------------
__global__ __launch_bounds__(256)
void transpose_split(const float* __restrict__ W, u16* __restrict__ Th,
                     u16* __restrict__ Tl, int K, int N) {
    __shared__ float t[32][33];
    const int tid = threadIdx.x;
    const int c  = tid & 31;
    const int r4 = tid >> 5;            // 0..7
    const int n0 = blockIdx.x * 32;
    const int k0 = blockIdx.y * 32;
#pragma unroll
    for (int i = 0; i < 4; ++i)
        t[r4*4+i][c] = W[(size_t)(k0 + r4*4 + i) * N + n0 + c];
    __syncthreads();
#pragma unroll
    for (int i = 0; i < 4; ++i) {
        const float v = t[c][r4*4+i];
        u16 h, l; splitf(v, h, l);
        const size_t o = (size_t)(n0 + r4*4 + i) * K + k0 + c;
        Th[o] = h; Tl[o] = l;
    }
}

// ---------------------------------------------------------------------------
// MFMA split-bf16 GEMM: C[M,N] = (Ah+Al)[M,K] @ (Bh+Bl)^T[N,K]^T  (+bias)
// B given TRANSPOSED [N][K]. 128x128 tile, BK=64, 4 waves (2x2 of 64x64).
// Staging: global_load_lds w=16 with inverse-swizzled source; fragment reads
// swizzled (byte ^= (row&7)<<4) -> conflict-free ds_read_b128.
// 3 MFMAs per frag-pair: Ah*Bh + Ah*Bl + Al*Bh (fp32-grade).
// ---------------------------------------------------------------------------
template<bool HAS_BIAS, bool F32_OUT, bool SPLIT_OUT>
__global__ __launch_bounds__(256, 2)
void gemm_mfma(const u16* __restrict__ Ah, const u16* __restrict__ Al,
               const u16* __restrict__ Bh, const u16* __restrict__ Bl,
               const float* __restrict__ bias, float* __restrict__ C,
               u16* __restrict__ Ch, u16* __restrict__ Cl,
               int M, int N, int K) {
    __shared__ u16 smem[4 * 8192];       // Ah | Al | Bh | Bl tiles, 16KB each
    const int tid  = threadIdx.x;
    const int wid  = tid >> 6;
    const int lane = tid & 63;
    const int lr   = lane & 15;
    const int kg   = lane >> 4;          // 0..3
    const int wr   = wid >> 1, wc = wid & 1;
    const int m0   = blockIdx.y * 128;
    const int n0   = blockIdx.x * 128;

    const u16* src = (wid == 0) ? Ah : (wid == 1) ? Al : (wid == 2) ? Bh : Bl;
    const int  rowbase = (wid < 2) ? m0 : n0;
    const bool isA     = (wid < 2);
    const int  subrow  = lane >> 3;              // 0..7
    const int  gslot   = (lane & 7) ^ subrow;    // inverse swizzle on source
    u16* tile = smem + wid * 8192;

    f32x4 acc[4][4];
#pragma unroll
    for (int i = 0; i < 4; ++i)
#pragma unroll
        for (int j = 0; j < 4; ++j) acc[i][j] = (f32x4)(0.f);

    for (int k0 = 0; k0 < K; k0 += 64) {
#pragma unroll
        for (int i = 0; i < 16; ++i) {
            int grow = rowbase + i*8 + subrow;
            if (isA && grow >= M) grow = M - 1;   // clamp tail rows (dup loads ok)
            const u16* g = src + (size_t)grow * K + (k0 + gslot * 8);
            gld_lds16(g, tile + i * 512);
        }
        __syncthreads();
#pragma unroll
        for (int ks = 0; ks < 2; ++ks) {
            bf16x8 ah[4], al[4], bh[4], bl[4];
            const int slot = (ks*4 + kg) ^ (lr & 7);
#pragma unroll
            for (int i = 0; i < 4; ++i) {
                const int offA = (wr*64 + i*16 + lr) * 64 + slot * 8;
                ah[i] = *(const bf16x8*)(smem + offA);
                al[i] = *(const bf16x8*)(smem + 8192 + offA);
                const int offB = (wc*64 + i*16 + lr) * 64 + slot * 8;
                bh[i] = *(const bf16x8*)(smem + 16384 + offB);
                bl[i] = *(const bf16x8*)(smem + 24576 + offB);
            }
#pragma unroll
            for (int i = 0; i < 4; ++i)
#pragma unroll
                for (int j = 0; j < 4; ++j) {
                    acc[i][j] = __builtin_amdgcn_mfma_f32_16x16x32_bf16(ah[i], bh[j], acc[i][j], 0, 0, 0);
                    acc[i][j] = __builtin_amdgcn_mfma_f32_16x16x32_bf16(ah[i], bl[j], acc[i][j], 0, 0, 0);
                    acc[i][j] = __builtin_amdgcn_mfma_f32_16x16x32_bf16(al[i], bh[j], acc[i][j], 0, 0, 0);
                }
        }
        __syncthreads();
    }
    // epilogue: D[row=(lane>>4)*4+e][col=lane&15] per 16x16 frag
    const int rb = lane >> 4;
    float bv[4];
    if (HAS_BIAS) {
#pragma unroll
        for (int j = 0; j < 4; ++j) bv[j] = bias[n0 + wc*64 + j*16 + lr];
    }
#pragma unroll
    for (int i = 0; i < 4; ++i)
#pragma unroll
        for (int e = 0; e < 4; ++e) {
            const int row = m0 + wr*64 + i*16 + rb*4 + e;
            if (row < M) {
#pragma unroll
                for (int j = 0; j < 4; ++j) {
                    const int col = n0 + wc*64 + j*16 + lr;
                    float v = acc[i][j][e];
                    if (HAS_BIAS) v += bv[j];
                    const size_t idx = (size_t)row * N + col;
                    if (F32_OUT) C[idx] = v;
                    if (SPLIT_OUT) { u16 h, l; splitf(v, h, l); Ch[idx] = h; Cl[idx] = l; }
                }
            }
        }
}

// ---------------------------------------------------------------------------
// 2x2 mean pools on split-bf16 latent
// ---------------------------------------------------------------------------
__device__ __forceinline__ float rec2(const u16* h, const u16* l, size_t i) {
    return bf2f(h[i]) + bf2f(l[i]);
}
__global__ __launch_bounds__(256)
void pool2_split(const u16* __restrict__ lh, const u16* __restrict__ ll,
                 u16* __restrict__ oh, u16* __restrict__ ol) {
    const int c = threadIdx.x;
    const int idx = blockIdx.x;            // b*144 + gh*12 + gw
    const int b = idx / 144;
    const int g = idx - b*144;
    const int gh = g / 12, gw = g - gh*12;
    const size_t i0 = (((size_t)(b*24 + gh*2))*24 + gw*2)*256 + c;
    const float s = (rec2(lh,ll,i0) + rec2(lh,ll,i0+256) +
                     rec2(lh,ll,i0+24*256) + rec2(lh,ll,i0+24*256+256)) * 0.25f;
    u16 h, l; splitf(s, h, l);
    oh[(size_t)idx*256 + c] = h; ol[(size_t)idx*256 + c] = l;
}
__global__ __launch_bounds__(256)
void pool4_split(const u16* __restrict__ lh, const u16* __restrict__ ll,
                 u16* __restrict__ oh, u16* __restrict__ ol) {
    const int c = threadIdx.x;
    const int idx = blockIdx.x;            // b*36 + gh*6 + gw
    const int b = idx / 36;
    const int g = idx - b*36;
    const int gh = g / 6, gw = g - gh*6;
    const size_t i0 = (((size_t)(b*12 + gh*2))*12 + gw*2)*256 + c;
    const float s = (rec2(lh,ll,i0) + rec2(lh,ll,i0+256) +
                     rec2(lh,ll,i0+12*256) + rec2(lh,ll,i0+12*256+256)) * 0.25f;
    u16 h, l; splitf(s, h, l);
    oh[(size_t)idx*256 + c] = h; ol[(size_t)idx*256 + c] = l;
}

// ---------------------------------------------------------------------------
// Fused attention (fp32, flash-style). ps LDS replaced by in-register exp
// values broadcast via __shfl (kills the 8-way bank conflicts of R1).
// ---------------------------------------------------------------------------
template<int S, int KS, int GW, bool WRITE>
__global__ __launch_bounds__(256)
void attn_kernel(const float* __restrict__ Q, const float* __restrict__ Km,
                 const float* __restrict__ Vm, const float* __restrict__ TBL,
                 float* __restrict__ CTX) {
    constexpr int TW = 2*GW - 1;
    __shared__ float qs[32][68];
    __shared__ float ks[32][68];
    __shared__ float vs[32][68];
    const int tid  = threadIdx.x;
    const int r    = tid >> 3;      // q-row in tile (0..31)
    const int dsub = tid & 7;       // dim group (8 floats)
    const int qt0  = blockIdx.x * 32;
    const int h    = blockIdx.y;
    const int b    = blockIdx.z;
    const int qg   = qt0 + r;
    const int qh   = qg / 24;
    const int qw   = qg - qh*24;
    {
        const float* qp = Q + ((size_t)(b*T_ + qg))*768 + h*64 + dsub*8;
        *(float4*)&qs[r][dsub*8]   = *(const float4*)qp;
        *(float4*)&qs[r][dsub*8+4] = *(const float4*)(qp+4);
    }
    const float* tblh = TBL + (size_t)h * (47 * TW);
    float acc[8];
#pragma unroll
    for (int i = 0; i < 8; ++i) acc[i] = 0.f;
    float mrow = -INFINITY, lrow = 0.f;

    for (int kt0 = 0; kt0 < KS; kt0 += 32) {
        __syncthreads();   // previous iter's PV reads of vs done
        {
            const int key = kt0 + r;
            if (key < KS) {
                const float* kp = Km + ((size_t)(b*KS + key))*768 + h*64 + dsub*8;
                *(float4*)&ks[r][dsub*8]   = *(const float4*)kp;
                *(float4*)&ks[r][dsub*8+4] = *(const float4*)(kp+4);
                const float* vp = Vm + ((size_t)(b*KS + key))*768 + h*64 + dsub*8;
                *(float4*)&vs[r][dsub*8]   = *(const float4*)vp;
                *(float4*)&vs[r][dsub*8+4] = *(const float4*)(vp+4);
            }
        }
        __syncthreads();
        float sc[4] = {0.f, 0.f, 0.f, 0.f};
#pragma unroll
        for (int d4 = 0; d4 < 16; ++d4) {
            const float4 a = *(const float4*)&qs[r][d4*4];
#pragma unroll
            for (int j = 0; j < 4; ++j) {
                const float4 kv = *(const float4*)&ks[dsub + 8*j][d4*4];
                sc[j] = fmaf(a.x, kv.x, sc[j]);
                sc[j] = fmaf(a.y, kv.y, sc[j]);
                sc[j] = fmaf(a.z, kv.z, sc[j]);
                sc[j] = fmaf(a.w, kv.w, sc[j]);
            }
        }
#pragma unroll
        for (int j = 0; j < 4; ++j) {
            const int c  = dsub + 8*j;
            const int kg = kt0 + c;
            if (kg < KS) {
                const int khi = kg / GW;
                const int kwi = kg - khi*GW;
                int rel_h, rel_w;
                if (S == 1) {
                    rel_h = qh - khi + 23;
                    rel_w = qw - kwi + (GW - 1);
                } else {
                    rel_h = (int)((float)qh - ((float)(khi*S) + 0.5f*(S-1))) + 23;
                    rel_w = (int)((float)qw - ((float)(kwi*S) + 0.5f*(S-1))) + (GW - 1);
                }
                sc[j] = fmaf(sc[j], 0.125f, tblh[rel_h*TW + rel_w]);
            } else {
                sc[j] = -INFINITY;
            }
        }
        float tmax = fmaxf(fmaxf(sc[0], sc[1]), fmaxf(sc[2], sc[3]));
        tmax = fmaxf(tmax, __shfl_xor(tmax, 1));
        tmax = fmaxf(tmax, __shfl_xor(tmax, 2));
        tmax = fmaxf(tmax, __shfl_xor(tmax, 4));
        const float newm   = fmaxf(mrow, tmax);
        const float factor = __expf(mrow - newm);
        float pj[4];
        float tsum = 0.f;
#pragma unroll
        for (int j = 0; j < 4; ++j) {
            pj[j] = __expf(sc[j] - newm);
            tsum += pj[j];
        }
        tsum += __shfl_xor(tsum, 1);
        tsum += __shfl_xor(tsum, 2);
        tsum += __shfl_xor(tsum, 4);
        lrow = lrow * factor + tsum;
        mrow = newm;
#pragma unroll
        for (int i = 0; i < 8; ++i) acc[i] *= factor;
        const int rl8 = (r & 7) << 3;   // this row's lane base within the wave
#pragma unroll
        for (int c = 0; c < 32; ++c) {
            const float p = __shfl(pj[c >> 3], rl8 | (c & 7), 64);
            const float4 v0 = *(const float4*)&vs[c][dsub*8];
            const float4 v1 = *(const float4*)&vs[c][dsub*8+4];
            acc[0] = fmaf(p, v0.x, acc[0]);
            acc[1] = fmaf(p, v0.y, acc[1]);
            acc[2] = fmaf(p, v0.z, acc[2]);
            acc[3] = fmaf(p, v0.w, acc[3]);
            acc[4] = fmaf(p, v1.x, acc[4]);
            acc[5] = fmaf(p, v1.y, acc[5]);
            acc[6] = fmaf(p, v1.z, acc[6]);
            acc[7] = fmaf(p, v1.w, acc[7]);
        }
    }
    const float invl = 1.0f / (3.0f * lrow);
    float* cp = CTX + ((size_t)(b*T_ + qg))*768 + h*64 + dsub*8;
    if (WRITE) {
        float4 o0, o1;
        o0.x = acc[0]*invl; o0.y = acc[1]*invl; o0.z = acc[2]*invl; o0.w = acc[3]*invl;
        o1.x = acc[4]*invl; o1.y = acc[5]*invl; o1.z = acc[6]*invl; o1.w = acc[7]*invl;
        *(float4*)cp     = o0;
        *(float4*)(cp+4) = o1;
    } else {
        float4 o0 = *(const float4*)cp;
        float4 o1 = *(const float4*)(cp+4);
        o0.x += acc[0]*invl; o0.y += acc[1]*invl; o0.z += acc[2]*invl; o0.w += acc[3]*invl;
        o1.x += acc[4]*invl; o1.y += acc[5]*invl; o1.z += acc[6]*invl; o1.w += acc[7]*invl;
        *(float4*)cp     = o0;
        *(float4*)(cp+4) = o1;
    }
}

// ---------------------------------------------------------------------------
extern "C" void kernel_launch(void* const* d_in, const int* in_sizes, int n_in,
                              void* d_out, int out_size, void* d_ws, size_t ws_size,
                              hipStream_t stream) {
    const float* x    = (const float*)d_in[0];
    const float* wq   = (const float*)d_in[1];
    const float* wdkv = (const float*)d_in[2];
    const float* wuk1 = (const float*)d_in[3];
    const float* wuk2 = (const float*)d_in[4];
    const float* wuk4 = (const float*)d_in[5];
    const float* wuv1 = (const float*)d_in[6];
    const float* wuv2 = (const float*)d_in[7];
    const float* wuv4 = (const float*)d_in[8];
    const float* wout = (const float*)d_in[9];
    const float* bout = (const float*)d_in[10];
    const float* tbl1 = (const float*)d_in[11];
    const float* tbl2 = (const float*)d_in[12];
    const float* tbl4 = (const float*)d_in[13];

    char* base = (char*)d_ws;
    // region A (28,311,552 B): xh/xl early, ctx fp32 later (serial stream)
    u16*   xh  = (u16*)base;
    u16*   xl  = xh + 7077888;
    float* ctx = (float*)base;
    // W region (10,223,616 B)
    u16* wqTh   = (u16*)(base + 28311552);
    u16* wqTl   = wqTh   + 589824;
    u16* wdkvTh = wqTl   + 589824;
    u16* wdkvTl = wdkvTh + 196608;
    u16* uk1h   = wdkvTl + 196608;
    u16* uk1l   = uk1h + 196608;
    u16* uv1h   = uk1l + 196608;
    u16* uv1l   = uv1h + 196608;
    u16* uk2h   = uv1l + 196608;
    u16* uk2l   = uk2h + 196608;
    u16* uv2h   = uk2l + 196608;
    u16* uv2l   = uv2h + 196608;
    u16* uk4h   = uv2l + 196608;
    u16* uk4l   = uk4h + 196608;
    u16* uv4h   = uk4l + 196608;
    u16* uv4l   = uv4h + 196608;
    u16* woutTh = uv4l + 196608;
    u16* woutTl = woutTh + 589824;
    // qb (28,311,552 B)
    float* qb = (float*)(base + 28311552 + 10223616);
    // lat/pool splits (12,386,304 B)
    u16* lath = (u16*)(base + 28311552 + 10223616 + 28311552);
    u16* latl = lath + 2359296;
    u16* lp2h = latl + 2359296;
    u16* lp2l = lp2h + 589824;
    u16* lp4h = lp2l + 589824;
    u16* lp4l = lp4h + 147456;
    // K region (56,623,104 B), serially reused: k1/v1 -> k2/v2 -> k4/v4 -> ctxh/ctxl
    char* kreg = base + 79233024;
    float* k1 = (float*)kreg;
    float* v1 = k1 + 7077888;
    float* k2 = (float*)kreg;
    float* v2 = k2 + 1769472;
    float* k4 = (float*)kreg;
    float* v4 = k4 + 442368;
    u16* ctxh = (u16*)kreg;
    u16* ctxl = ctxh + 7077888;
    float* outp = (float*)d_out;

    // ---- input conversions ----
    convert_split<<<6912, 256, 0, stream>>>(x, xh, xl, 7077888);
    transpose_split<<<dim3(24,24), 256, 0, stream>>>(wq,   wqTh,   wqTl,   768, 768);
    transpose_split<<<dim3( 8,24), 256, 0, stream>>>(wdkv, wdkvTh, wdkvTl, 768, 256);
    transpose_split<<<dim3(24, 8), 256, 0, stream>>>(wuk1, uk1h, uk1l, 256, 768);
    transpose_split<<<dim3(24, 8), 256, 0, stream>>>(wuv1, uv1h, uv1l, 256, 768);
    transpose_split<<<dim3(24, 8), 256, 0, stream>>>(wuk2, uk2h, uk2l, 256, 768);
    transpose_split<<<dim3(24, 8), 256, 0, stream>>>(wuv2, uv2h, uv2l, 256, 768);
    transpose_split<<<dim3(24, 8), 256, 0, stream>>>(wuk4, uk4h, uk4l, 256, 768);
    transpose_split<<<dim3(24, 8), 256, 0, stream>>>(wuv4, uv4h, uv4l, 256, 768);
    transpose_split<<<dim3(24,24), 256, 0, stream>>>(wout, woutTh, woutTl, 768, 768);

    // ---- projections ----
    gemm_mfma<false,true ,false><<<dim3(6,72), 256, 0, stream>>>(xh, xl, wqTh, wqTl, nullptr, qb, nullptr, nullptr, 9216, 768, 768);
    gemm_mfma<false,false,true ><<<dim3(2,72), 256, 0, stream>>>(xh, xl, wdkvTh, wdkvTl, nullptr, nullptr, lath, latl, 9216, 256, 768);
    pool2_split<<<16*144, 256, 0, stream>>>(lath, latl, lp2h, lp2l);
    pool4_split<<<16*36,  256, 0, stream>>>(lp2h, lp2l, lp4h, lp4l);

    // ---- scale 1 ----
    gemm_mfma<false,true ,false><<<dim3(6,72), 256, 0, stream>>>(lath, latl, uk1h, uk1l, nullptr, k1, nullptr, nullptr, 9216, 768, 256);
    gemm_mfma<false,true ,false><<<dim3(6,72), 256, 0, stream>>>(lath, latl, uv1h, uv1l, nullptr, v1, nullptr, nullptr, 9216, 768, 256);
    attn_kernel<1, 576, 24, true ><<<dim3(18, NH_, B_), 256, 0, stream>>>(qb, k1, v1, tbl1, ctx);
    // ---- scale 2 (reuses K region) ----
    gemm_mfma<false,true ,false><<<dim3(6,18), 256, 0, stream>>>(lp2h, lp2l, uk2h, uk2l, nullptr, k2, nullptr, nullptr, 2304, 768, 256);
    gemm_mfma<false,true ,false><<<dim3(6,18), 256, 0, stream>>>(lp2h, lp2l, uv2h, uv2l, nullptr, v2, nullptr, nullptr, 2304, 768, 256);
    attn_kernel<2, 144, 12, false><<<dim3(18, NH_, B_), 256, 0, stream>>>(qb, k2, v2, tbl2, ctx);
    // ---- scale 4 ----
    gemm_mfma<false,true ,false><<<dim3(6,5), 256, 0, stream>>>(lp4h, lp4l, uk4h, uk4l, nullptr, k4, nullptr, nullptr, 576, 768, 256);
    gemm_mfma<false,true ,false><<<dim3(6,5), 256, 0, stream>>>(lp4h, lp4l, uv4h, uv4l, nullptr, v4, nullptr, nullptr, 576, 768, 256);
    attn_kernel<4,  36,  6, false><<<dim3(18, NH_, B_), 256, 0, stream>>>(qb, k4, v4, tbl4, ctx);

    // ---- output projection ----
    convert_split<<<6912, 256, 0, stream>>>(ctx, ctxh, ctxl, 7077888);
    gemm_mfma<true ,true ,false><<<dim3(6,72), 256, 0, stream>>>(ctxh, ctxl, woutTh, woutTl, bout, outp, nullptr, nullptr, 9216, 768, 768);
}

// Round 3
// 433.028 us; speedup vs baseline: 3.2745x; 2.4566x over previous
//
#include <hip/hip_runtime.h>
#include <hip/hip_bf16.h>
#include <math.h>

#define B_   16
#define T_   576
#define NH_  12

typedef unsigned short u16;
typedef __attribute__((ext_vector_type(8))) short bf16x8;
typedef __attribute__((ext_vector_type(4))) float f32x4;

// ---------------------------------------------------------------------------
// bf16 helpers
// ---------------------------------------------------------------------------
__device__ __forceinline__ float bf2f(u16 u) {
    union { unsigned int i; float f; } x; x.i = ((unsigned int)u) << 16; return x.f;
}
__device__ __forceinline__ u16 f2bf(float f) {   // round-to-nearest-even
    union { float f; unsigned int i; } x; x.f = f;
    unsigned int r = x.i + 0x7fffu + ((x.i >> 16) & 1u);
    return (u16)(r >> 16);
}
__device__ __forceinline__ void splitf(float v, u16& h, u16& l) {
    h = f2bf(v);
    l = f2bf(v - bf2f(h));
}
__device__ __forceinline__ void gld_lds16(const u16* g, u16* l) {
    __builtin_amdgcn_global_load_lds(
        (const __attribute__((address_space(1))) unsigned int*)g,
        (__attribute__((address_space(3))) unsigned int*)l, 16, 0, 0);
}

// ---------------------------------------------------------------------------
// fp32 -> bf16 (plain), 8 elems/thread
// ---------------------------------------------------------------------------
__global__ __launch_bounds__(256)
void convert_bf(const float* __restrict__ in, u16* __restrict__ out, int n) {
    const int i8 = (blockIdx.x * 256 + threadIdx.x) * 8;
    if (i8 >= n) return;
    const float4 a = *(const float4*)&in[i8];
    const float4 b = *(const float4*)&in[i8 + 4];
    u16 o[8] = {f2bf(a.x),f2bf(a.y),f2bf(a.z),f2bf(a.w),
                f2bf(b.x),f2bf(b.y),f2bf(b.z),f2bf(b.w)};
    *(bf16x8*)&out[i8] = *(bf16x8*)o;
}

// fp32 -> (hi,lo) bf16 split, 4 elems/thread
__global__ __launch_bounds__(256)
void convert_split(const float* __restrict__ in, u16* __restrict__ h,
                   u16* __restrict__ l, int n) {
    const int i4 = (blockIdx.x * 256 + threadIdx.x) * 4;
    if (i4 >= n) return;
    const float4 v = *(const float4*)&in[i4];
    u16 h0,h1,h2,h3, l0,l1,l2,l3;
    splitf(v.x,h0,l0); splitf(v.y,h1,l1); splitf(v.z,h2,l2); splitf(v.w,h3,l3);
    *(ushort4*)&h[i4] = make_ushort4(h0,h1,h2,h3);
    *(ushort4*)&l[i4] = make_ushort4(l0,l1,l2,l3);
}

// ---------------------------------------------------------------------------
// W[K][N] fp32 -> T[N][K] bf16 (optionally split). grid (N/32, K/32)
// ---------------------------------------------------------------------------
template<bool SPLIT>
__global__ __launch_bounds__(256)
void transpose_wt(const float* __restrict__ W, u16* __restrict__ Th,
                  u16* __restrict__ Tl, int K, int N) {
    __shared__ float t[32][33];
    const int tid = threadIdx.x;
    const int c  = tid & 31;
    const int r4 = tid >> 5;            // 0..7
    const int n0 = blockIdx.x * 32;
    const int k0 = blockIdx.y * 32;
#pragma unroll
    for (int i = 0; i < 4; ++i)
        t[r4*4+i][c] = W[(size_t)(k0 + r4*4 + i) * N + n0 + c];
    __syncthreads();
#pragma unroll
    for (int i = 0; i < 4; ++i) {
        const float v = t[c][r4*4+i];
        const size_t o = (size_t)(n0 + r4*4 + i) * K + k0 + c;
        if (SPLIT) { u16 h, l; splitf(v, h, l); Th[o] = h; Tl[o] = l; }
        else       { Th[o] = f2bf(v); }
    }
}

// ---------------------------------------------------------------------------
// MFMA GEMM. IN_SPLIT: A,B split (3 mfma) else plain (1 mfma).
// OUT_MODE: 0 = fp32 (+bias), 1 = bf16 [M][N], 2 = bf16 transposed [b][N][KSt].
// B given TRANSPOSED [N][K]. 128x128 tile, BK=64, 4 waves.
// ---------------------------------------------------------------------------
template<bool IN_SPLIT, int OUT_MODE, bool HAS_BIAS>
__global__ __launch_bounds__(256, 2)
void gemm_mfma(const u16* __restrict__ Ah, const u16* __restrict__ Al,
               const u16* __restrict__ Bh, const u16* __restrict__ Bl,
               const float* __restrict__ bias, float* __restrict__ C,
               u16* __restrict__ Cbf, int M, int N, int K, int KSt) {
    __shared__ u16 smem[(IN_SPLIT ? 4 : 2) * 8192];
    const int tid  = threadIdx.x;
    const int wid  = tid >> 6;
    const int lane = tid & 63;
    const int lr   = lane & 15;
    const int kg   = lane >> 4;
    const int wr   = wid >> 1, wc = wid & 1;
    const int m0   = blockIdx.y * 128;
    const int n0   = blockIdx.x * 128;
    const int subrow = lane >> 3;
    const int gslot  = (lane & 7) ^ subrow;     // inverse swizzle on source

    const u16* src; int rowbase; bool isA; u16* tile;
    constexpr int NITER = IN_SPLIT ? 16 : 8;
    if (IN_SPLIT) {
        src = (wid == 0) ? Ah : (wid == 1) ? Al : (wid == 2) ? Bh : Bl;
        rowbase = (wid < 2) ? m0 : n0;
        isA = (wid < 2);
        tile = smem + wid * 8192;
    } else {
        src = (wid < 2) ? Ah : Bh;
        rowbase = ((wid < 2) ? m0 : n0) + (wid & 1) * 64;
        isA = (wid < 2);
        tile = smem + (wid >> 1) * 8192 + (wid & 1) * 4096;
    }

    f32x4 acc[4][4];
#pragma unroll
    for (int i = 0; i < 4; ++i)
#pragma unroll
        for (int j = 0; j < 4; ++j) acc[i][j] = (f32x4)(0.f);

    for (int k0 = 0; k0 < K; k0 += 64) {
#pragma unroll
        for (int i = 0; i < NITER; ++i) {
            int grow = rowbase + i*8 + subrow;
            if (isA && grow >= M) grow = M - 1;   // clamp tail (dup loads ok)
            gld_lds16(src + (size_t)grow * K + (k0 + gslot * 8), tile + i * 512);
        }
        __syncthreads();
#pragma unroll
        for (int ks = 0; ks < 2; ++ks) {
            const int slot = (ks*4 + kg) ^ (lr & 7);
            bf16x8 ah[4], bh[4], al[4], bl[4];
#pragma unroll
            for (int i = 0; i < 4; ++i) {
                const int offA = (wr*64 + i*16 + lr) * 64 + slot * 8;
                const int offB = (wc*64 + i*16 + lr) * 64 + slot * 8;
                ah[i] = *(const bf16x8*)(smem + offA);
                bh[i] = *(const bf16x8*)(smem + (IN_SPLIT ? 16384 : 8192) + offB);
                if (IN_SPLIT) {
                    al[i] = *(const bf16x8*)(smem + 8192  + offA);
                    bl[i] = *(const bf16x8*)(smem + 24576 + offB);
                }
            }
#pragma unroll
            for (int i = 0; i < 4; ++i)
#pragma unroll
                for (int j = 0; j < 4; ++j) {
                    acc[i][j] = __builtin_amdgcn_mfma_f32_16x16x32_bf16(ah[i], bh[j], acc[i][j], 0, 0, 0);
                    if (IN_SPLIT) {
                        acc[i][j] = __builtin_amdgcn_mfma_f32_16x16x32_bf16(ah[i], bl[j], acc[i][j], 0, 0, 0);
                        acc[i][j] = __builtin_amdgcn_mfma_f32_16x16x32_bf16(al[i], bh[j], acc[i][j], 0, 0, 0);
                    }
                }
        }
        __syncthreads();
    }
    const int rb = lane >> 4;
    float bv[4];
    if (HAS_BIAS) {
#pragma unroll
        for (int j = 0; j < 4; ++j) bv[j] = bias[n0 + wc*64 + j*16 + lr];
    }
#pragma unroll
    for (int i = 0; i < 4; ++i)
#pragma unroll
        for (int e = 0; e < 4; ++e) {
            const int row = m0 + wr*64 + i*16 + rb*4 + e;
            if (row < M) {
#pragma unroll
                for (int j = 0; j < 4; ++j) {
                    const int col = n0 + wc*64 + j*16 + lr;
                    float v = acc[i][j][e];
                    if (HAS_BIAS) v += bv[j];
                    if (OUT_MODE == 0) {
                        C[(size_t)row * N + col] = v;
                    } else if (OUT_MODE == 1) {
                        Cbf[(size_t)row * N + col] = f2bf(v);
                    } else {
                        const int bidx = row / KSt;
                        const int key  = row - bidx * KSt;
                        Cbf[((size_t)bidx * N + col) * KSt + key] = f2bf(v);
                    }
                }
            }
        }
}

// ---------------------------------------------------------------------------
// 2x2 mean pools on bf16
// ---------------------------------------------------------------------------
__global__ __launch_bounds__(256)
void pool2_bf(const u16* __restrict__ in, u16* __restrict__ out) {
    const int c = threadIdx.x;
    const int idx = blockIdx.x;            // b*144 + gh*12 + gw
    const int b = idx / 144;
    const int g = idx - b*144;
    const int gh = g / 12, gw = g - gh*12;
    const size_t i0 = (((size_t)(b*24 + gh*2))*24 + gw*2)*256 + c;
    const float s = (bf2f(in[i0]) + bf2f(in[i0+256]) +
                     bf2f(in[i0+24*256]) + bf2f(in[i0+24*256+256])) * 0.25f;
    out[(size_t)idx*256 + c] = f2bf(s);
}
__global__ __launch_bounds__(256)
void pool4_bf(const u16* __restrict__ in, u16* __restrict__ out) {
    const int c = threadIdx.x;
    const int idx = blockIdx.x;            // b*36 + gh*6 + gw
    const int b = idx / 36;
    const int g = idx - b*36;
    const int gh = g / 6, gw = g - gh*6;
    const size_t i0 = (((size_t)(b*12 + gh*2))*12 + gw*2)*256 + c;
    const float s = (bf2f(in[i0]) + bf2f(in[i0+256]) +
                     bf2f(in[i0+12*256]) + bf2f(in[i0+12*256+256])) * 0.25f;
    out[(size_t)idx*256 + c] = f2bf(s);
}

// ---------------------------------------------------------------------------
// MFMA flash attention, one scale. Grid (T/64, NH, B), 256 thr = 4 waves.
// Wave w owns q rows [q0+w*16, +16). Per 32-key tile:
//   scores = mfma(Q, K) (C-layout: key=lane&15, qrow=(lane>>4)*4+e)
//   + bias (on-the-fly table gather) -> online softmax in registers
//   P -> wave-private LDS (bf16) -> A-frag; PV = mfma(P, Vt).
// CTX: WRITE ? store : accumulate (+= 1/3 each scale via invl).
// ---------------------------------------------------------------------------
template<int KS, int GW, int S, bool WRITE>
__global__ __launch_bounds__(256)
void attn_mfma(const u16* __restrict__ Qbf, const u16* __restrict__ Kbf,
               const u16* __restrict__ Vt, const float* __restrict__ TBL,
               float* __restrict__ CTX) {
    constexpr int TW = 2*GW - 1;
    __shared__ u16 Kl[32][72];     // padded: 144B rows
    __shared__ u16 Vl[64][40];     // padded: 80B rows (Vt: [d][key])
    __shared__ u16 Pl[4][16][40];  // per-wave P, padded
    const int tid  = threadIdx.x;
    const int wid  = tid >> 6;
    const int lane = tid & 63;
    const int lr   = lane & 15;
    const int kg   = lane >> 4;
    const int b    = blockIdx.z;
    const int h    = blockIdx.y;
    const int q0   = blockIdx.x * 64;
    const int qw0  = q0 + wid * 16;

    // Q A-frags (rows at lane&15, k at kg*8+e)
    bf16x8 qa[2];
    {
        const u16* qp = Qbf + ((size_t)(b*T_) + qw0 + lr)*768 + h*64 + kg*8;
        qa[0] = *(const bf16x8*)qp;
        qa[1] = *(const bf16x8*)(qp + 32);
    }
    // per-lane softmax rows: q = qw0 + kg*4 + e
    int qh_e[4], qw_e[4];
#pragma unroll
    for (int e = 0; e < 4; ++e) {
        const int q = qw0 + kg*4 + e;
        qh_e[e] = q / 24; qw_e[e] = q - qh_e[e]*24;
    }
    const float* tblh = TBL + (size_t)h * (47 * TW);

    f32x4 acc[4];
#pragma unroll
    for (int j = 0; j < 4; ++j) acc[j] = (f32x4)(0.f);
    float m[4]    = {-1e30f, -1e30f, -1e30f, -1e30f};
    float lsum[4] = {0.f, 0.f, 0.f, 0.f};

    for (int kt0 = 0; kt0 < KS; kt0 += 32) {
        __syncthreads();
        {   // stage K tile: thread t -> key=t>>3, 16B chunk slot=t&7
            const int key = tid >> 3, slot = tid & 7;
            const int gk = kt0 + key;
            bf16x8 kv = {0,0,0,0,0,0,0,0};
            if (gk < KS)
                kv = *(const bf16x8*)(Kbf + ((size_t)b*KS + gk)*768 + h*64 + slot*8);
            *(bf16x8*)&Kl[key][slot*8] = kv;
        }
        {   // stage Vt tile: thread t -> d=t>>2, 8-key chunk slot=t&3
            const int d = tid >> 2, slot = tid & 3;
            const int kbase = kt0 + slot*8;
            const u16* vp = Vt + ((size_t)b*768 + h*64 + d)*KS + kbase;
            bf16x8 vv = {0,0,0,0,0,0,0,0};
            if (kbase + 7 < KS) {
                vv = *(const bf16x8*)vp;
            } else {
#pragma unroll
                for (int u = 0; u < 8; ++u)
                    if (kbase + u < KS) vv[u] = (short)vp[u];
            }
            *(bf16x8*)&Vl[d][slot*8] = vv;
        }
        __syncthreads();

        // scores: 2 key-groups x 2 k-slices
        f32x4 sf[2] = {(f32x4)(0.f), (f32x4)(0.f)};
#pragma unroll
        for (int g = 0; g < 2; ++g)
#pragma unroll
            for (int ks = 0; ks < 2; ++ks) {
                const bf16x8 kb = *(const bf16x8*)&Kl[g*16 + lr][ks*32 + kg*8];
                sf[g] = __builtin_amdgcn_mfma_f32_16x16x32_bf16(qa[ks], kb, sf[g], 0, 0, 0);
            }

        // bias + mask
        float sc[2][4];
#pragma unroll
        for (int g = 0; g < 2; ++g) {
            const int key = kt0 + g*16 + lr;
            const bool valid = (key < KS);
            int khi = 0, kwi = 0;
            if (valid) { khi = key / GW; kwi = key - khi*GW; }
#pragma unroll
            for (int e = 0; e < 4; ++e) {
                if (valid) {
                    int rel_h, rel_w;
                    if (S == 1) {
                        rel_h = qh_e[e] - khi + 23;
                        rel_w = qw_e[e] - kwi + (GW - 1);
                    } else {
                        rel_h = (int)((float)qh_e[e] - ((float)(khi*S) + 0.5f*(S-1))) + 23;
                        rel_w = (int)((float)qw_e[e] - ((float)(kwi*S) + 0.5f*(S-1))) + (GW - 1);
                    }
                    sc[g][e] = fmaf(sf[g][e], 0.125f, tblh[rel_h*TW + rel_w]);
                } else {
                    sc[g][e] = -1e30f;
                }
            }
        }

        // online softmax (reduce across 16 lanes sharing a row group)
#pragma unroll
        for (int e = 0; e < 4; ++e) {
            float rm = fmaxf(sc[0][e], sc[1][e]);
            rm = fmaxf(rm, __shfl_xor(rm, 1));
            rm = fmaxf(rm, __shfl_xor(rm, 2));
            rm = fmaxf(rm, __shfl_xor(rm, 4));
            rm = fmaxf(rm, __shfl_xor(rm, 8));
            const float nm  = fmaxf(m[e], rm);
            const float fac = __expf(m[e] - nm);
            const float p0 = __expf(sc[0][e] - nm);
            const float p1 = __expf(sc[1][e] - nm);
            float ts = p0 + p1;
            ts += __shfl_xor(ts, 1);
            ts += __shfl_xor(ts, 2);
            ts += __shfl_xor(ts, 4);
            ts += __shfl_xor(ts, 8);
            lsum[e] = lsum[e] * fac + ts;
            m[e] = nm;
#pragma unroll
            for (int j = 0; j < 4; ++j) acc[j][e] *= fac;
            Pl[wid][kg*4 + e][lr]      = f2bf(p0);
            Pl[wid][kg*4 + e][16 + lr] = f2bf(p1);
        }

        // PV: A = P (rows at lane&15, keys kg*8+e), B = Vt
        {
            const bf16x8 pa = *(const bf16x8*)&Pl[wid][lr][kg*8];
#pragma unroll
            for (int j = 0; j < 4; ++j) {
                const bf16x8 vb = *(const bf16x8*)&Vl[j*16 + lr][kg*8];
                acc[j] = __builtin_amdgcn_mfma_f32_16x16x32_bf16(pa, vb, acc[j], 0, 0, 0);
            }
        }
    }

    // epilogue
#pragma unroll
    for (int e = 0; e < 4; ++e) {
        const float inv = 1.0f / (3.0f * lsum[e]);
        float* cp = CTX + ((size_t)(b*T_) + qw0 + kg*4 + e)*768 + h*64 + lr;
#pragma unroll
        for (int j = 0; j < 4; ++j) {
            const float v = acc[j][e] * inv;
            if (WRITE) cp[j*16] = v;
            else       cp[j*16] += v;
        }
    }
}

// ---------------------------------------------------------------------------
extern "C" void kernel_launch(void* const* d_in, const int* in_sizes, int n_in,
                              void* d_out, int out_size, void* d_ws, size_t ws_size,
                              hipStream_t stream) {
    const float* x    = (const float*)d_in[0];
    const float* wq   = (const float*)d_in[1];
    const float* wdkv = (const float*)d_in[2];
    const float* wuk1 = (const float*)d_in[3];
    const float* wuk2 = (const float*)d_in[4];
    const float* wuk4 = (const float*)d_in[5];
    const float* wuv1 = (const float*)d_in[6];
    const float* wuv2 = (const float*)d_in[7];
    const float* wuv4 = (const float*)d_in[8];
    const float* wout = (const float*)d_in[9];
    const float* bout = (const float*)d_in[10];
    const float* tbl1 = (const float*)d_in[11];
    const float* tbl2 = (const float*)d_in[12];
    const float* tbl4 = (const float*)d_in[13];

    char* base = (char*)d_ws;
    u16* x_bf   = (u16*)base;                        // 7077888
    u16* q_bf   = x_bf   + 7077888;                  // 7077888
    u16* lat_bf = q_bf   + 7077888;                  // 2359296
    u16* lp2_bf = lat_bf + 2359296;                  // 589824
    u16* lp4_bf = lp2_bf + 589824;                   // 147456
    u16* wqT    = lp4_bf + 147456;                   // 589824
    u16* wdkvT  = wqT    + 589824;                   // 196608
    u16* uk1T   = wdkvT  + 196608;                   // 196608
    u16* uv1T   = uk1T   + 196608;
    u16* uk2T   = uv1T   + 196608;
    u16* uv2T   = uk2T   + 196608;
    u16* uk4T   = uv2T   + 196608;
    u16* uv4T   = uk4T   + 196608;
    u16* woutTh = uv4T   + 196608;                   // 589824
    u16* woutTl = woutTh + 589824;                   // 589824
    u16* k1     = woutTl + 589824;                   // 7077888
    u16* v1t    = k1     + 7077888;                  // 7077888
    u16* ctxh   = k1;                                // alias (k1/v1t dead by then)
    u16* ctxl   = ctxh   + 7077888;
    u16* k2     = v1t    + 7077888;                  // 1769472
    u16* v2t    = k2     + 1769472;                  // 1769472
    u16* k4     = v2t    + 1769472;                  // 442368
    u16* v4t    = k4     + 442368;                   // 442368
    float* ctx  = (float*)(v4t + 442368);            // 7077888 f32
    float* outp = (float*)d_out;

    // ---- conversions ----
    convert_bf<<<3456, 256, 0, stream>>>(x, x_bf, 7077888);
    transpose_wt<false><<<dim3(24,24), 256, 0, stream>>>(wq,   wqT,   nullptr, 768, 768);
    transpose_wt<false><<<dim3( 8,24), 256, 0, stream>>>(wdkv, wdkvT, nullptr, 768, 256);
    transpose_wt<false><<<dim3(24, 8), 256, 0, stream>>>(wuk1, uk1T, nullptr, 256, 768);
    transpose_wt<false><<<dim3(24, 8), 256, 0, stream>>>(wuv1, uv1T, nullptr, 256, 768);
    transpose_wt<false><<<dim3(24, 8), 256, 0, stream>>>(wuk2, uk2T, nullptr, 256, 768);
    transpose_wt<false><<<dim3(24, 8), 256, 0, stream>>>(wuv2, uv2T, nullptr, 256, 768);
    transpose_wt<false><<<dim3(24, 8), 256, 0, stream>>>(wuk4, uk4T, nullptr, 256, 768);
    transpose_wt<false><<<dim3(24, 8), 256, 0, stream>>>(wuv4, uv4T, nullptr, 256, 768);
    transpose_wt<true ><<<dim3(24,24), 256, 0, stream>>>(wout, woutTh, woutTl, 768, 768);

    // ---- projections (plain bf16) ----
    gemm_mfma<false,1,false><<<dim3(6,72), 256, 0, stream>>>(x_bf, nullptr, wqT, nullptr, nullptr, nullptr, q_bf, 9216, 768, 768, 0);
    gemm_mfma<false,1,false><<<dim3(2,72), 256, 0, stream>>>(x_bf, nullptr, wdkvT, nullptr, nullptr, nullptr, lat_bf, 9216, 256, 768, 0);
    pool2_bf<<<16*144, 256, 0, stream>>>(lat_bf, lp2_bf);
    pool4_bf<<<16*36,  256, 0, stream>>>(lp2_bf, lp4_bf);

    // ---- scale 1 ----
    gemm_mfma<false,1,false><<<dim3(6,72), 256, 0, stream>>>(lat_bf, nullptr, uk1T, nullptr, nullptr, nullptr, k1,  9216, 768, 256, 0);
    gemm_mfma<false,2,false><<<dim3(6,72), 256, 0, stream>>>(lat_bf, nullptr, uv1T, nullptr, nullptr, nullptr, v1t, 9216, 768, 256, 576);
    attn_mfma<576,24,1,true ><<<dim3(9, NH_, B_), 256, 0, stream>>>(q_bf, k1, v1t, tbl1, ctx);
    // ---- scale 2 ----
    gemm_mfma<false,1,false><<<dim3(6,18), 256, 0, stream>>>(lp2_bf, nullptr, uk2T, nullptr, nullptr, nullptr, k2,  2304, 768, 256, 0);
    gemm_mfma<false,2,false><<<dim3(6,18), 256, 0, stream>>>(lp2_bf, nullptr, uv2T, nullptr, nullptr, nullptr, v2t, 2304, 768, 256, 144);
    attn_mfma<144,12,2,false><<<dim3(9, NH_, B_), 256, 0, stream>>>(q_bf, k2, v2t, tbl2, ctx);
    // ---- scale 4 ----
    gemm_mfma<false,1,false><<<dim3(6,5), 256, 0, stream>>>(lp4_bf, nullptr, uk4T, nullptr, nullptr, nullptr, k4,  576, 768, 256, 0);
    gemm_mfma<false,2,false><<<dim3(6,5), 256, 0, stream>>>(lp4_bf, nullptr, uv4T, nullptr, nullptr, nullptr, v4t, 576, 768, 256, 36);
    attn_mfma<36,6,4,false><<<dim3(9, NH_, B_), 256, 0, stream>>>(q_bf, k4, v4t, tbl4, ctx);

    // ---- output projection (split for accuracy) ----
    convert_split<<<6912, 256, 0, stream>>>(ctx, ctxh, ctxl, 7077888);
    gemm_mfma<true,0,true><<<dim3(6,72), 256, 0, stream>>>(ctxh, ctxl, woutTh, woutTl, bout, outp, nullptr, 9216, 768, 768, 0);
}

// Round 4
// 370.983 us; speedup vs baseline: 3.8221x; 1.1672x over previous
//
#include <hip/hip_runtime.h>
#include <hip/hip_bf16.h>
#include <math.h>

#define B_   16
#define T_   576
#define NH_  12

typedef unsigned short u16;
typedef __attribute__((ext_vector_type(8))) short bf16x8;
typedef __attribute__((ext_vector_type(4))) float f32x4;

// ---------------------------------------------------------------------------
// bf16 helpers
// ---------------------------------------------------------------------------
__device__ __forceinline__ float bf2f(u16 u) {
    union { unsigned int i; float f; } x; x.i = ((unsigned int)u) << 16; return x.f;
}
__device__ __forceinline__ u16 f2bf(float f) {   // round-to-nearest-even
    union { float f; unsigned int i; } x; x.f = f;
    unsigned int r = x.i + 0x7fffu + ((x.i >> 16) & 1u);
    return (u16)(r >> 16);
}
__device__ __forceinline__ void splitf(float v, u16& h, u16& l) {
    h = f2bf(v);
    l = f2bf(v - bf2f(h));
}
__device__ __forceinline__ void gld_lds16(const u16* g, u16* l) {
    __builtin_amdgcn_global_load_lds(
        (const __attribute__((address_space(1))) unsigned int*)g,
        (__attribute__((address_space(3))) unsigned int*)l, 16, 0, 0);
}

// ---------------------------------------------------------------------------
// fp32 -> bf16 (plain), 8 elems/thread
// ---------------------------------------------------------------------------
__global__ __launch_bounds__(256)
void convert_bf(const float* __restrict__ in, u16* __restrict__ out, int n) {
    const int i8 = (blockIdx.x * 256 + threadIdx.x) * 8;
    if (i8 >= n) return;
    const float4 a = *(const float4*)&in[i8];
    const float4 b = *(const float4*)&in[i8 + 4];
    u16 o[8] = {f2bf(a.x),f2bf(a.y),f2bf(a.z),f2bf(a.w),
                f2bf(b.x),f2bf(b.y),f2bf(b.z),f2bf(b.w)};
    *(bf16x8*)&out[i8] = *(bf16x8*)o;
}

// ---------------------------------------------------------------------------
// W[K][N] fp32 -> T[N][K] bf16 (optionally split). grid (N/32, K/32)
// ---------------------------------------------------------------------------
template<bool SPLIT>
__global__ __launch_bounds__(256)
void transpose_wt(const float* __restrict__ W, u16* __restrict__ Th,
                  u16* __restrict__ Tl, int K, int N) {
    __shared__ float t[32][33];
    const int tid = threadIdx.x;
    const int c  = tid & 31;
    const int r4 = tid >> 5;            // 0..7
    const int n0 = blockIdx.x * 32;
    const int k0 = blockIdx.y * 32;
#pragma unroll
    for (int i = 0; i < 4; ++i)
        t[r4*4+i][c] = W[(size_t)(k0 + r4*4 + i) * N + n0 + c];
    __syncthreads();
#pragma unroll
    for (int i = 0; i < 4; ++i) {
        const float v = t[c][r4*4+i];
        const size_t o = (size_t)(n0 + r4*4 + i) * K + k0 + c;
        if (SPLIT) { u16 h, l; splitf(v, h, l); Th[o] = h; Tl[o] = l; }
        else       { Th[o] = f2bf(v); }
    }
}

// ---------------------------------------------------------------------------
// MFMA GEMM. IN_SPLIT: A,B split (3 mfma) else plain (1 mfma).
// OUT_MODE: 0 = fp32 (+bias), 1 = bf16 [M][N], 2 = bf16 transposed [b][N][KSt].
// B given TRANSPOSED [N][K]. 128x128 tile, BK=64, 4 waves.
// ---------------------------------------------------------------------------
template<bool IN_SPLIT, int OUT_MODE, bool HAS_BIAS>
__global__ __launch_bounds__(256, 2)
void gemm_mfma(const u16* __restrict__ Ah, const u16* __restrict__ Al,
               const u16* __restrict__ Bh, const u16* __restrict__ Bl,
               const float* __restrict__ bias, float* __restrict__ C,
               u16* __restrict__ Cbf, int M, int N, int K, int KSt) {
    __shared__ u16 smem[(IN_SPLIT ? 4 : 2) * 8192];
    const int tid  = threadIdx.x;
    const int wid  = tid >> 6;
    const int lane = tid & 63;
    const int lr   = lane & 15;
    const int kg   = lane >> 4;
    const int wr   = wid >> 1, wc = wid & 1;
    const int m0   = blockIdx.y * 128;
    const int n0   = blockIdx.x * 128;
    const int subrow = lane >> 3;
    const int gslot  = (lane & 7) ^ subrow;     // inverse swizzle on source

    const u16* src; int rowbase; bool isA; u16* tile;
    constexpr int NITER = IN_SPLIT ? 16 : 8;
    if (IN_SPLIT) {
        src = (wid == 0) ? Ah : (wid == 1) ? Al : (wid == 2) ? Bh : Bl;
        rowbase = (wid < 2) ? m0 : n0;
        isA = (wid < 2);
        tile = smem + wid * 8192;
    } else {
        src = (wid < 2) ? Ah : Bh;
        rowbase = ((wid < 2) ? m0 : n0) + (wid & 1) * 64;
        isA = (wid < 2);
        tile = smem + (wid >> 1) * 8192 + (wid & 1) * 4096;
    }

    f32x4 acc[4][4];
#pragma unroll
    for (int i = 0; i < 4; ++i)
#pragma unroll
        for (int j = 0; j < 4; ++j) acc[i][j] = (f32x4)(0.f);

    for (int k0 = 0; k0 < K; k0 += 64) {
#pragma unroll
        for (int i = 0; i < NITER; ++i) {
            int grow = rowbase + i*8 + subrow;
            if (isA && grow >= M) grow = M - 1;   // clamp tail (dup loads ok)
            gld_lds16(src + (size_t)grow * K + (k0 + gslot * 8), tile + i * 512);
        }
        __syncthreads();
#pragma unroll
        for (int ks = 0; ks < 2; ++ks) {
            const int slot = (ks*4 + kg) ^ (lr & 7);
            bf16x8 ah[4], bh[4], al[4], bl[4];
#pragma unroll
            for (int i = 0; i < 4; ++i) {
                const int offA = (wr*64 + i*16 + lr) * 64 + slot * 8;
                const int offB = (wc*64 + i*16 + lr) * 64 + slot * 8;
                ah[i] = *(const bf16x8*)(smem + offA);
                bh[i] = *(const bf16x8*)(smem + (IN_SPLIT ? 16384 : 8192) + offB);
                if (IN_SPLIT) {
                    al[i] = *(const bf16x8*)(smem + 8192  + offA);
                    bl[i] = *(const bf16x8*)(smem + 24576 + offB);
                }
            }
#pragma unroll
            for (int i = 0; i < 4; ++i)
#pragma unroll
                for (int j = 0; j < 4; ++j) {
                    acc[i][j] = __builtin_amdgcn_mfma_f32_16x16x32_bf16(ah[i], bh[j], acc[i][j], 0, 0, 0);
                    if (IN_SPLIT) {
                        acc[i][j] = __builtin_amdgcn_mfma_f32_16x16x32_bf16(ah[i], bl[j], acc[i][j], 0, 0, 0);
                        acc[i][j] = __builtin_amdgcn_mfma_f32_16x16x32_bf16(al[i], bh[j], acc[i][j], 0, 0, 0);
                    }
                }
        }
        __syncthreads();
    }
    const int rb = lane >> 4;
    float bv[4];
    if (HAS_BIAS) {
#pragma unroll
        for (int j = 0; j < 4; ++j) bv[j] = bias[n0 + wc*64 + j*16 + lr];
    }
#pragma unroll
    for (int i = 0; i < 4; ++i)
#pragma unroll
        for (int e = 0; e < 4; ++e) {
            const int row = m0 + wr*64 + i*16 + rb*4 + e;
            if (row < M) {
#pragma unroll
                for (int j = 0; j < 4; ++j) {
                    const int col = n0 + wc*64 + j*16 + lr;
                    float v = acc[i][j][e];
                    if (HAS_BIAS) v += bv[j];
                    if (OUT_MODE == 0) {
                        C[(size_t)row * N + col] = v;
                    } else if (OUT_MODE == 1) {
                        Cbf[(size_t)row * N + col] = f2bf(v);
                    } else {
                        const int bidx = row / KSt;
                        const int key  = row - bidx * KSt;
                        Cbf[((size_t)bidx * N + col) * KSt + key] = f2bf(v);
                    }
                }
            }
        }
}

// ---------------------------------------------------------------------------
// 2x2 mean pools on bf16
// ---------------------------------------------------------------------------
__global__ __launch_bounds__(256)
void pool2_bf(const u16* __restrict__ in, u16* __restrict__ out) {
    const int c = threadIdx.x;
    const int idx = blockIdx.x;            // b*144 + gh*12 + gw
    const int b = idx / 144;
    const int g = idx - b*144;
    const int gh = g / 12, gw = g - gh*12;
    const size_t i0 = (((size_t)(b*24 + gh*2))*24 + gw*2)*256 + c;
    const float s = (bf2f(in[i0]) + bf2f(in[i0+256]) +
                     bf2f(in[i0+24*256]) + bf2f(in[i0+24*256+256])) * 0.25f;
    out[(size_t)idx*256 + c] = f2bf(s);
}
__global__ __launch_bounds__(256)
void pool4_bf(const u16* __restrict__ in, u16* __restrict__ out) {
    const int c = threadIdx.x;
    const int idx = blockIdx.x;            // b*36 + gh*6 + gw
    const int b = idx / 36;
    const int g = idx - b*36;
    const int gh = g / 6, gw = g - gh*6;
    const size_t i0 = (((size_t)(b*12 + gh*2))*12 + gw*2)*256 + c;
    const float s = (bf2f(in[i0]) + bf2f(in[i0+256]) +
                     bf2f(in[i0+12*256]) + bf2f(in[i0+12*256+256])) * 0.25f;
    out[(size_t)idx*256 + c] = f2bf(s);
}

// ---------------------------------------------------------------------------
// One attention scale, 64-key tiles, fixed-max softmax (scores provably
// tiny: |qk/8 + bias| < ~1, so exp() without max-subtraction is safe and
// mathematically identical after normalization).
// Score layout (mfma C): q-row = kg*4+e, key = g*16+lr.
// ---------------------------------------------------------------------------
template<int KS, int GW, int S>
__device__ __forceinline__ void attn_scale(
    const u16* __restrict__ Kbf, const u16* __restrict__ Vt,
    const float* __restrict__ TBL,
    const bf16x8 qa[2], const int qh_e[4], const int qw_e[4],
    int b, int h, int tid, int lr, int kg,
    u16 (*Kl)[72], u16 (*Vl)[72], u16* PlW,
    f32x4 octx[4])
{
    constexpr int TW = 2*GW - 1;
    constexpr int NT = (KS + 63) / 64;
    const float* tblh = TBL + (size_t)h * (47 * TW);
    int base_e[4];
#pragma unroll
    for (int e = 0; e < 4; ++e)
        base_e[e] = (qh_e[e] + 23) * TW + qw_e[e] + (GW - 1);

    f32x4 pacc[4];
#pragma unroll
    for (int j = 0; j < 4; ++j) pacc[j] = (f32x4)(0.f);
    float plsum[4] = {0.f, 0.f, 0.f, 0.f};

    const int keyS = tid & 63;          // staged key (K) / dim (V)
    const int c2   = tid >> 6;          // 16B chunk pair

    for (int t = 0; t < NT; ++t) {
        const int kt0 = t * 64;
        __syncthreads();
        {   // stage K [64 keys][64 dims] and Vt [64 dims][64 keys]
            const u16* kp = Kbf + ((size_t)b*KS + kt0 + keyS)*768 + h*64;
            *(bf16x8*)&Kl[keyS][c2*8]     = *(const bf16x8*)(kp + c2*8);
            *(bf16x8*)&Kl[keyS][(c2+4)*8] = *(const bf16x8*)(kp + (c2+4)*8);
            const u16* vp = Vt + ((size_t)b*768 + h*64 + keyS)*KS + kt0;
            *(bf16x8*)&Vl[keyS][c2*8]     = *(const bf16x8*)(vp + c2*8);
            *(bf16x8*)&Vl[keyS][(c2+4)*8] = *(const bf16x8*)(vp + (c2+4)*8);
        }
        __syncthreads();

        f32x4 sf[4];
#pragma unroll
        for (int g = 0; g < 4; ++g) sf[g] = (f32x4)(0.f);
#pragma unroll
        for (int ks = 0; ks < 2; ++ks)
#pragma unroll
            for (int g = 0; g < 4; ++g) {
                const bf16x8 kb = *(const bf16x8*)&Kl[g*16 + lr][ks*32 + kg*8];
                sf[g] = __builtin_amdgcn_mfma_f32_16x16x32_bf16(qa[ks], kb, sf[g], 0, 0, 0);
            }

#pragma unroll
        for (int g = 0; g < 4; ++g) {
            const int key = kt0 + g*16 + lr;
            const bool valid = (KS % 64 == 0) || (key < KS);
            const int khi = key / GW;
            const int kwi = key - khi*GW;
            float pv[4];
            if (S == 1) {
                const int off = khi*TW + kwi;
#pragma unroll
                for (int e = 0; e < 4; ++e)
                    pv[e] = valid ? __expf(fmaf(sf[g][e], 0.125f, tblh[base_e[e] - off])) : 0.f;
            } else {
#pragma unroll
                for (int e = 0; e < 4; ++e) {
                    float p = 0.f;
                    if (valid) {
                        const int dh = qh_e[e] - S*khi;     // trunc-to-zero semantics
                        const int dw = qw_e[e] - S*kwi;
                        int rh, rw;
                        if (S == 2) { rh = dh - (dh >= 1) + 23;     rw = dw - (dw >= 1) + (GW-1); }
                        else        { rh = dh - 1 - (dh >= 2) + 23; rw = dw - 1 - (dw >= 2) + (GW-1); }
                        p = __expf(fmaf(sf[g][e], 0.125f, tblh[rh*TW + rw]));
                    }
                    pv[e] = p;
                }
            }
#pragma unroll
            for (int e = 0; e < 4; ++e) {
                plsum[e] += pv[e];
                PlW[(kg*4 + e)*72 + g*16 + lr] = f2bf(pv[e]);
            }
        }

        // PV (Pl written/read by same wave -> no barrier)
#pragma unroll
        for (int ks = 0; ks < 2; ++ks) {
            const bf16x8 pa = *(const bf16x8*)&PlW[lr*72 + ks*32 + kg*8];
#pragma unroll
            for (int j = 0; j < 4; ++j) {
                const bf16x8 vb = *(const bf16x8*)&Vl[j*16 + lr][ks*32 + kg*8];
                pacc[j] = __builtin_amdgcn_mfma_f32_16x16x32_bf16(pa, vb, pacc[j], 0, 0, 0);
            }
        }
    }

    // one cross-lane sum reduction per scale
#pragma unroll
    for (int e = 0; e < 4; ++e) {
        float l = plsum[e];
        l += __shfl_xor(l, 1);
        l += __shfl_xor(l, 2);
        l += __shfl_xor(l, 4);
        l += __shfl_xor(l, 8);
        const float inv = 1.0f / (3.0f * l);
#pragma unroll
        for (int j = 0; j < 4; ++j) octx[j][e] = fmaf(pacc[j][e], inv, octx[j][e]);
    }
}

// ---------------------------------------------------------------------------
// Fused 3-scale attention. 1-D grid, bid = qtile*192 + (b*12+h) so the 9
// q-tiles sharing one (b,h) K/V slice land on the SAME XCD (192 % 8 == 0)
// -> K/V stay L2-resident (~4.4 MB/XCD).
// Epilogue writes split hi/lo bf16 ctx directly (final GEMM input).
// ---------------------------------------------------------------------------
__global__ __launch_bounds__(256)
void attn_fused(const u16* __restrict__ Qbf,
                const u16* __restrict__ K1, const u16* __restrict__ V1t,
                const u16* __restrict__ K2, const u16* __restrict__ V2t,
                const u16* __restrict__ K4, const u16* __restrict__ V4t,
                const float* __restrict__ T1, const float* __restrict__ T2,
                const float* __restrict__ T4,
                u16* __restrict__ Ch, u16* __restrict__ Cl) {
    __shared__ u16 Kl[64][72];
    __shared__ u16 Vl[64][72];
    __shared__ u16 Pl[4][16][72];
    const int tid  = threadIdx.x;
    const int wid  = tid >> 6;
    const int lane = tid & 63;
    const int lr   = lane & 15;
    const int kg   = lane >> 4;
    const int bid  = blockIdx.x;
    const int qt   = bid / 192;
    const int bh   = bid - qt*192;
    const int b    = bh / 12;
    const int h    = bh - b*12;
    const int qw0  = qt*64 + wid*16;

    bf16x8 qa[2];
    {
        const u16* qp = Qbf + ((size_t)(b*T_) + qw0 + lr)*768 + h*64 + kg*8;
        qa[0] = *(const bf16x8*)qp;
        qa[1] = *(const bf16x8*)(qp + 32);
    }
    int qh_e[4], qw_e[4];
#pragma unroll
    for (int e = 0; e < 4; ++e) {
        const int q = qw0 + kg*4 + e;
        qh_e[e] = q / 24; qw_e[e] = q - qh_e[e]*24;
    }
    f32x4 octx[4];
#pragma unroll
    for (int j = 0; j < 4; ++j) octx[j] = (f32x4)(0.f);
    u16* PlW = &Pl[wid][0][0];

    attn_scale<576,24,1>(K1, V1t, T1, qa, qh_e, qw_e, b, h, tid, lr, kg, Kl, Vl, PlW, octx);
    attn_scale<144,12,2>(K2, V2t, T2, qa, qh_e, qw_e, b, h, tid, lr, kg, Kl, Vl, PlW, octx);
    attn_scale< 36, 6,4>(K4, V4t, T4, qa, qh_e, qw_e, b, h, tid, lr, kg, Kl, Vl, PlW, octx);

#pragma unroll
    for (int e = 0; e < 4; ++e) {
        const size_t rowoff = ((size_t)(b*T_) + qw0 + kg*4 + e)*768 + h*64;
#pragma unroll
        for (int j = 0; j < 4; ++j) {
            u16 hh, ll; splitf(octx[j][e], hh, ll);
            Ch[rowoff + j*16 + lr] = hh;
            Cl[rowoff + j*16 + lr] = ll;
        }
    }
}

// ---------------------------------------------------------------------------
extern "C" void kernel_launch(void* const* d_in, const int* in_sizes, int n_in,
                              void* d_out, int out_size, void* d_ws, size_t ws_size,
                              hipStream_t stream) {
    const float* x    = (const float*)d_in[0];
    const float* wq   = (const float*)d_in[1];
    const float* wdkv = (const float*)d_in[2];
    const float* wuk1 = (const float*)d_in[3];
    const float* wuk2 = (const float*)d_in[4];
    const float* wuk4 = (const float*)d_in[5];
    const float* wuv1 = (const float*)d_in[6];
    const float* wuv2 = (const float*)d_in[7];
    const float* wuv4 = (const float*)d_in[8];
    const float* wout = (const float*)d_in[9];
    const float* bout = (const float*)d_in[10];
    const float* tbl1 = (const float*)d_in[11];
    const float* tbl2 = (const float*)d_in[12];
    const float* tbl4 = (const float*)d_in[13];

    u16* p = (u16*)d_ws;
    u16* x_bf   = p;            p += 7077888;
    u16* q_bf   = p;            p += 7077888;
    u16* lat_bf = p;            p += 2359296;
    u16* lp2_bf = p;            p += 589824;
    u16* lp4_bf = p;            p += 147456;
    u16* wqT    = p;            p += 589824;
    u16* wdkvT  = p;            p += 196608;
    u16* uk1T   = p;            p += 196608;
    u16* uv1T   = p;            p += 196608;
    u16* uk2T   = p;            p += 196608;
    u16* uv2T   = p;            p += 196608;
    u16* uk4T   = p;            p += 196608;
    u16* uv4T   = p;            p += 196608;
    u16* woutTh = p;            p += 589824;
    u16* woutTl = p;            p += 589824;
    u16* k1     = p;            p += 7077888;
    u16* v1t    = p;            p += 7077888;
    u16* k2     = p;            p += 1769472;
    u16* v2t    = p;            p += 1769472;
    u16* k4     = p;            p += 442368;
    u16* v4t    = p;            p += 442368;
    u16* ctxh   = p;            p += 7077888;
    u16* ctxl   = p;            p += 7077888;
    float* outp = (float*)d_out;

    // ---- conversions ----
    convert_bf<<<3456, 256, 0, stream>>>(x, x_bf, 7077888);
    transpose_wt<false><<<dim3(24,24), 256, 0, stream>>>(wq,   wqT,   nullptr, 768, 768);
    transpose_wt<false><<<dim3( 8,24), 256, 0, stream>>>(wdkv, wdkvT, nullptr, 768, 256);
    transpose_wt<false><<<dim3(24, 8), 256, 0, stream>>>(wuk1, uk1T, nullptr, 256, 768);
    transpose_wt<false><<<dim3(24, 8), 256, 0, stream>>>(wuv1, uv1T, nullptr, 256, 768);
    transpose_wt<false><<<dim3(24, 8), 256, 0, stream>>>(wuk2, uk2T, nullptr, 256, 768);
    transpose_wt<false><<<dim3(24, 8), 256, 0, stream>>>(wuv2, uv2T, nullptr, 256, 768);
    transpose_wt<false><<<dim3(24, 8), 256, 0, stream>>>(wuk4, uk4T, nullptr, 256, 768);
    transpose_wt<false><<<dim3(24, 8), 256, 0, stream>>>(wuv4, uv4T, nullptr, 256, 768);
    transpose_wt<true ><<<dim3(24,24), 256, 0, stream>>>(wout, woutTh, woutTl, 768, 768);

    // ---- projections (plain bf16) ----
    gemm_mfma<false,1,false><<<dim3(6,72), 256, 0, stream>>>(x_bf, nullptr, wqT, nullptr, nullptr, nullptr, q_bf, 9216, 768, 768, 0);
    gemm_mfma<false,1,false><<<dim3(2,72), 256, 0, stream>>>(x_bf, nullptr, wdkvT, nullptr, nullptr, nullptr, lat_bf, 9216, 256, 768, 0);
    pool2_bf<<<16*144, 256, 0, stream>>>(lat_bf, lp2_bf);
    pool4_bf<<<16*36,  256, 0, stream>>>(lp2_bf, lp4_bf);

    // ---- K/V up-projections ----
    gemm_mfma<false,1,false><<<dim3(6,72), 256, 0, stream>>>(lat_bf, nullptr, uk1T, nullptr, nullptr, nullptr, k1,  9216, 768, 256, 0);
    gemm_mfma<false,2,false><<<dim3(6,72), 256, 0, stream>>>(lat_bf, nullptr, uv1T, nullptr, nullptr, nullptr, v1t, 9216, 768, 256, 576);
    gemm_mfma<false,1,false><<<dim3(6,18), 256, 0, stream>>>(lp2_bf, nullptr, uk2T, nullptr, nullptr, nullptr, k2,  2304, 768, 256, 0);
    gemm_mfma<false,2,false><<<dim3(6,18), 256, 0, stream>>>(lp2_bf, nullptr, uv2T, nullptr, nullptr, nullptr, v2t, 2304, 768, 256, 144);
    gemm_mfma<false,1,false><<<dim3(6,5), 256, 0, stream>>>(lp4_bf, nullptr, uk4T, nullptr, nullptr, nullptr, k4,  576, 768, 256, 0);
    gemm_mfma<false,2,false><<<dim3(6,5), 256, 0, stream>>>(lp4_bf, nullptr, uv4T, nullptr, nullptr, nullptr, v4t, 576, 768, 256, 36);

    // ---- fused 3-scale attention ----
    attn_fused<<<9*192, 256, 0, stream>>>(q_bf, k1, v1t, k2, v2t, k4, v4t,
                                          tbl1, tbl2, tbl4, ctxh, ctxl);

    // ---- output projection (split for accuracy) ----
    gemm_mfma<true,0,true><<<dim3(6,72), 256, 0, stream>>>(ctxh, ctxl, woutTh, woutTl, bout, outp, nullptr, 9216, 768, 768, 0);
}

// Round 6
// 330.981 us; speedup vs baseline: 4.2841x; 1.1209x over previous
//
#include <hip/hip_runtime.h>
#include <hip/hip_bf16.h>
#include <math.h>

#define B_   16
#define T_   576
#define NH_  12

typedef unsigned short u16;
typedef __attribute__((ext_vector_type(8))) short bf16x8;
typedef __attribute__((ext_vector_type(4))) float f32x4;

// ---------------------------------------------------------------------------
// helpers
// ---------------------------------------------------------------------------
__device__ __forceinline__ float bf2f(u16 u) {
    union { unsigned int i; float f; } x; x.i = ((unsigned int)u) << 16; return x.f;
}
__device__ __forceinline__ u16 f2bf(float f) {   // round-to-nearest-even
    union { float f; unsigned int i; } x; x.f = f;
    unsigned int r = x.i + 0x7fffu + ((x.i >> 16) & 1u);
    return (u16)(r >> 16);
}
__device__ __forceinline__ void splitf(float v, u16& h, u16& l) {
    h = f2bf(v);
    l = f2bf(v - bf2f(h));
}
__device__ __forceinline__ void gld_lds16(const u16* g, u16* l) {
    __builtin_amdgcn_global_load_lds(
        (const __attribute__((address_space(1))) unsigned int*)g,
        (__attribute__((address_space(3))) unsigned int*)l, 16, 0, 0);
}
__device__ __forceinline__ float exp2f_(float x) {
#if __has_builtin(__builtin_amdgcn_exp2f)
    return __builtin_amdgcn_exp2f(x);
#else
    return exp2f(x);
#endif
}

// ---------------------------------------------------------------------------
// fp32 -> bf16 (plain), 8 elems/thread
// ---------------------------------------------------------------------------
__global__ __launch_bounds__(256)
void convert_bf(const float* __restrict__ in, u16* __restrict__ out, int n) {
    const int i8 = (blockIdx.x * 256 + threadIdx.x) * 8;
    if (i8 >= n) return;
    const float4 a = *(const float4*)&in[i8];
    const float4 b = *(const float4*)&in[i8 + 4];
    u16 o[8] = {f2bf(a.x),f2bf(a.y),f2bf(a.z),f2bf(a.w),
                f2bf(b.x),f2bf(b.y),f2bf(b.z),f2bf(b.w)};
    *(bf16x8*)&out[i8] = *(bf16x8*)o;
}

// ---------------------------------------------------------------------------
// All weight transposes in one kernel (flat block id decode).
// ---------------------------------------------------------------------------
__global__ __launch_bounds__(256)
void prep_weights(const float* __restrict__ wq, const float* __restrict__ wdkv,
                  const float* __restrict__ uk1, const float* __restrict__ uv1,
                  const float* __restrict__ uk2, const float* __restrict__ uv2,
                  const float* __restrict__ uk4, const float* __restrict__ uv4,
                  const float* __restrict__ wout,
                  u16* wqT, u16* wdkvT, u16* uk1T, u16* uv1T, u16* uk2T,
                  u16* uv2T, u16* uk4T, u16* uv4T, u16* woutTh, u16* woutTl) {
    int id = blockIdx.x;
    const float* W; u16* Th; u16* Tl = nullptr; int K, N, gx; bool split = false;
    if (id < 576)       { W = wq;  Th = wqT;  K = 768; N = 768; gx = 24; }
    else if (id < 768)  { id -= 576; W = wdkv; Th = wdkvT; K = 768; N = 256; gx = 8; }
    else if (id < 1920) {
        id -= 768; const int w = id / 192; id -= w * 192;
        const float* Ws[6] = {uk1, uv1, uk2, uv2, uk4, uv4};
        u16* Ts[6] = {uk1T, uv1T, uk2T, uv2T, uk4T, uv4T};
        W = Ws[w]; Th = Ts[w]; K = 256; N = 768; gx = 24;
    } else { id -= 1920; W = wout; Th = woutTh; Tl = woutTl; K = 768; N = 768; gx = 24; split = true; }
    const int bx = id % gx, by = id / gx;
    const int n0 = bx * 32, k0 = by * 32;

    __shared__ float t[32][33];
    const int tid = threadIdx.x;
    const int c  = tid & 31;
    const int r4 = tid >> 5;
#pragma unroll
    for (int i = 0; i < 4; ++i)
        t[r4*4+i][c] = W[(size_t)(k0 + r4*4 + i) * N + n0 + c];
    __syncthreads();
#pragma unroll
    for (int i = 0; i < 4; ++i) {
        const float v = t[c][r4*4+i];
        const size_t o = (size_t)(n0 + r4*4 + i) * K + k0 + c;
        if (split) { u16 h, l; splitf(v, h, l); Th[o] = h; Tl[o] = l; }
        else       { Th[o] = f2bf(v); }
    }
}

// ---------------------------------------------------------------------------
// MFMA GEMM, optionally dual-B (cols >= N1 use B2/OM2 path).
// IN_SPLIT: A,B split (3 mfma). OM: 0 = fp32 (+bias), 1 = bf16 [M][N],
// 2 = bf16 transposed [b][N][KSt], -1 = unused.
// B transposed [N][K]. 128x128 tile, BK=64, 4 waves.
// ---------------------------------------------------------------------------
template<bool IN_SPLIT, int OM1, int OM2, bool HAS_BIAS>
__global__ __launch_bounds__(256, 2)
void gemm_mfma(const u16* __restrict__ Ah, const u16* __restrict__ Al,
               const u16* __restrict__ B1h, const u16* __restrict__ B1l,
               const u16* __restrict__ B2h,
               const float* __restrict__ bias, float* __restrict__ C1f,
               u16* __restrict__ C1bf, u16* __restrict__ C2bf,
               int M, int N1, int N2, int K, int KSt) {
    __shared__ u16 smem[(IN_SPLIT ? 4 : 2) * 8192];
    const int tid  = threadIdx.x;
    const int wid  = tid >> 6;
    const int lane = tid & 63;
    const int lr   = lane & 15;
    const int kg   = lane >> 4;
    const int wr   = wid >> 1, wc = wid & 1;
    const int m0   = blockIdx.y * 128;
    const int n0   = blockIdx.x * 128;
    const bool second = (OM2 >= 0) && (n0 >= N1);
    const int nb   = second ? n0 - N1 : n0;
    const int subrow = lane >> 3;
    const int gslot  = (lane & 7) ^ subrow;     // inverse swizzle on source

    const u16* src; int rowbase; bool isA; u16* tile;
    constexpr int NITER = IN_SPLIT ? 16 : 8;
    if (IN_SPLIT) {
        src = (wid == 0) ? Ah : (wid == 1) ? Al : (wid == 2) ? B1h : B1l;
        rowbase = (wid < 2) ? m0 : n0;
        isA = (wid < 2);
        tile = smem + wid * 8192;
    } else {
        const u16* Bsel = second ? B2h : B1h;
        src = (wid < 2) ? Ah : Bsel;
        rowbase = ((wid < 2) ? m0 : nb) + (wid & 1) * 64;
        isA = (wid < 2);
        tile = smem + (wid >> 1) * 8192 + (wid & 1) * 4096;
    }

    f32x4 acc[4][4];
#pragma unroll
    for (int i = 0; i < 4; ++i)
#pragma unroll
        for (int j = 0; j < 4; ++j) acc[i][j] = (f32x4)(0.f);

    for (int k0 = 0; k0 < K; k0 += 64) {
#pragma unroll
        for (int i = 0; i < NITER; ++i) {
            int grow = rowbase + i*8 + subrow;
            if (isA && grow >= M) grow = M - 1;   // clamp tail (dup loads ok)
            gld_lds16(src + (size_t)grow * K + (k0 + gslot * 8), tile + i * 512);
        }
        __syncthreads();
#pragma unroll
        for (int ks = 0; ks < 2; ++ks) {
            const int slot = (ks*4 + kg) ^ (lr & 7);
            bf16x8 ah[4], bh[4], al[4], bl[4];
#pragma unroll
            for (int i = 0; i < 4; ++i) {
                const int offA = (wr*64 + i*16 + lr) * 64 + slot * 8;
                const int offB = (wc*64 + i*16 + lr) * 64 + slot * 8;
                ah[i] = *(const bf16x8*)(smem + offA);
                bh[i] = *(const bf16x8*)(smem + (IN_SPLIT ? 16384 : 8192) + offB);
                if (IN_SPLIT) {
                    al[i] = *(const bf16x8*)(smem + 8192  + offA);
                    bl[i] = *(const bf16x8*)(smem + 24576 + offB);
                }
            }
#pragma unroll
            for (int i = 0; i < 4; ++i)
#pragma unroll
                for (int j = 0; j < 4; ++j) {
                    acc[i][j] = __builtin_amdgcn_mfma_f32_16x16x32_bf16(ah[i], bh[j], acc[i][j], 0, 0, 0);
                    if (IN_SPLIT) {
                        acc[i][j] = __builtin_amdgcn_mfma_f32_16x16x32_bf16(ah[i], bl[j], acc[i][j], 0, 0, 0);
                        acc[i][j] = __builtin_amdgcn_mfma_f32_16x16x32_bf16(al[i], bh[j], acc[i][j], 0, 0, 0);
                    }
                }
        }
        __syncthreads();
    }
    const int rb = lane >> 4;
    float bv[4];
    if (HAS_BIAS) {
#pragma unroll
        for (int j = 0; j < 4; ++j) bv[j] = bias[n0 + wc*64 + j*16 + lr];
    }
#pragma unroll
    for (int i = 0; i < 4; ++i)
#pragma unroll
        for (int e = 0; e < 4; ++e) {
            const int row = m0 + wr*64 + i*16 + rb*4 + e;
            if (row < M) {
#pragma unroll
                for (int j = 0; j < 4; ++j) {
                    const int colw = wc*64 + j*16 + lr;
                    float v = acc[i][j][e];
                    if (HAS_BIAS) v += bv[j];
                    if (!second) {
                        const int col = n0 + colw;
                        if (OM1 == 0) C1f[(size_t)row * N1 + col] = v;
                        else if (OM1 == 1) C1bf[(size_t)row * N1 + col] = f2bf(v);
                        else {
                            const int bidx = row / KSt, key = row - bidx * KSt;
                            C1bf[((size_t)bidx * N1 + col) * KSt + key] = f2bf(v);
                        }
                    } else {
                        const int col = nb + colw;
                        if (OM2 == 1) C2bf[(size_t)row * N2 + col] = f2bf(v);
                        else if (OM2 == 2) {
                            const int bidx = row / KSt, key = row - bidx * KSt;
                            C2bf[((size_t)bidx * N2 + col) * KSt + key] = f2bf(v);
                        }
                    }
                }
            }
        }
}

// ---------------------------------------------------------------------------
// Both mean pools from lat in one kernel. blocks [0,2304)=lp2, [2304,2880)=lp4
// ---------------------------------------------------------------------------
__global__ __launch_bounds__(256)
void pool_both(const u16* __restrict__ lat, u16* __restrict__ lp2,
               u16* __restrict__ lp4) {
    const int c = threadIdx.x;
    int id = blockIdx.x;
    if (id < 2304) {
        const int b = id / 144, g = id - b*144;
        const int gh = g / 12, gw = g - gh*12;
        const size_t i0 = (((size_t)(b*24 + gh*2))*24 + gw*2)*256 + c;
        const float s = (bf2f(lat[i0]) + bf2f(lat[i0+256]) +
                         bf2f(lat[i0+24*256]) + bf2f(lat[i0+24*256+256])) * 0.25f;
        lp2[(size_t)id*256 + c] = f2bf(s);
    } else {
        id -= 2304;
        const int b = id / 36, g = id - b*36;
        const int gh = g / 6, gw = g - gh*6;
        const size_t base = (((size_t)(b*24 + gh*4))*24 + gw*4)*256 + c;
        float s = 0.f;
#pragma unroll
        for (int i = 0; i < 4; ++i)
#pragma unroll
            for (int j = 0; j < 4; ++j)
                s += bf2f(lat[base + (size_t)(i*24 + j)*256]);
        lp4[(size_t)id*256 + c] = f2bf(s * (1.f/16.f));
    }
}

// ---------------------------------------------------------------------------
// One attention scale, swapped-operand form.
// QK: S^T = mfma(K, Q)  -> lane holds keys (kg*4+e per group g), q = lr.
// P write: pair-packed f2bf (RNE) u32s, rows = q (lane-local).
// PV: out^T = mfma(V^T, P^T) -> octx[j][e] = out[q=lr][d=j*16+kg*4+e].
// Fixed-max softmax in log2 domain; bias table staged in LDS as fp32*log2e.
// ---------------------------------------------------------------------------
template<int KS, int GW, int S>
__device__ __forceinline__ void attn_scale(
    const u16* __restrict__ Kbf, const u16* __restrict__ Vt,
    const float* __restrict__ TBL,
    const bf16x8 qa[2], int qh, int qw, int b, int h,
    int tid, int lr, int kg,
    u16 (*Kl)[72], u16 (*Vl)[72], u16* PlW, float* TblL,
    f32x4 octx[4])
{
    constexpr int TW  = 2*GW - 1;
    constexpr int NT  = (KS + 63) / 64;
    constexpr int NTB = 47 * TW;
    constexpr float C1 = 0.18033688011112042f;   // 0.125 * log2(e)

    __syncthreads();   // previous scale done with TblL/Kl/Vl
    for (int i = tid; i < NTB; i += 256)
        TblL[i] = TBL[(size_t)h * NTB + i] * 1.4426950408889634f;

    const int base1 = (qh + 23)*TW + qw + (GW - 1);    // S==1 flat base
    f32x4 pacc[4];
#pragma unroll
    for (int j = 0; j < 4; ++j) pacc[j] = (f32x4)(0.f);
    float ls = 0.f;

    const int keyS = tid & 63;
    const int c2   = tid >> 6;

    for (int t = 0; t < NT; ++t) {
        const int kt0 = t * 64;
        __syncthreads();
        {   // stage K [key][d]
            const u16* kp = Kbf + ((size_t)b*KS + kt0 + keyS)*768 + h*64;
            *(bf16x8*)&Kl[keyS][c2*8]     = *(const bf16x8*)(kp + c2*8);
            *(bf16x8*)&Kl[keyS][(c2+4)*8] = *(const bf16x8*)(kp + (c2+4)*8);
            // stage Vt [d][key] (guard tails; keep loads 16B-aligned)
            const u16* vp = Vt + ((size_t)b*768 + h*64 + keyS)*KS;
            const int kb0 = kt0 + c2*8;
            const int kb1 = kt0 + 32 + c2*8;
            if ((KS % 8) == 0 && ((KS % 64) == 0 || kb0 + 8 <= KS)) {
                *(bf16x8*)&Vl[keyS][c2*8] = *(const bf16x8*)(vp + kb0);
            } else {
                bf16x8 vv = {0,0,0,0,0,0,0,0};
#pragma unroll
                for (int u = 0; u < 8; ++u) if (kb0 + u < KS) vv[u] = (short)vp[kb0+u];
                *(bf16x8*)&Vl[keyS][c2*8] = vv;
            }
            if ((KS % 8) == 0 && ((KS % 64) == 0 || kb1 + 8 <= KS)) {
                *(bf16x8*)&Vl[keyS][(c2+4)*8] = *(const bf16x8*)(vp + kb1);
            } else {
                bf16x8 vv = {0,0,0,0,0,0,0,0};
#pragma unroll
                for (int u = 0; u < 8; ++u) if (kb1 + u < KS) vv[u] = (short)vp[kb1+u];
                *(bf16x8*)&Vl[keyS][(c2+4)*8] = vv;
            }
        }
        __syncthreads();

        // S^T = K . Q^T
        f32x4 sf[4] = {(f32x4)(0.f), (f32x4)(0.f), (f32x4)(0.f), (f32x4)(0.f)};
        __builtin_amdgcn_s_setprio(1);
#pragma unroll
        for (int ks = 0; ks < 2; ++ks)
#pragma unroll
            for (int g = 0; g < 4; ++g) {
                const bf16x8 kb = *(const bf16x8*)&Kl[g*16 + lr][ks*32 + kg*8];
                sf[g] = __builtin_amdgcn_mfma_f32_16x16x32_bf16(kb, qa[ks], sf[g], 0, 0, 0);
            }
        __builtin_amdgcn_s_setprio(0);

        // softmax (fixed max) + pack P rows (f2bf = RNE; ls from pre-quant
        // floats, matching the R4-validated numerics)
#pragma unroll
        for (int g = 0; g < 4; ++g) {
            const int key0 = kt0 + g*16 + kg*4;
            const bool v4 = ((KS % 64) == 0) || (key0 < KS);
            const int khi  = key0 / GW;
            const int kwi0 = key0 - khi*GW;
            float pv[4];
            if (S == 1) {
                const int idx0 = base1 - khi*TW - kwi0;
#pragma unroll
                for (int e = 0; e < 4; ++e)
                    pv[e] = exp2f_(fmaf(sf[g][e], C1, TblL[idx0 - e]));
            } else if (S == 2) {
                const int dh = qh - 2*khi;
                const int rh = dh - (dh >= 1) + 23;
#pragma unroll
                for (int e = 0; e < 4; ++e) {
                    const int dw = qw - 2*(kwi0 + e);
                    const int rw = dw - (dw >= 1) + (GW - 1);
                    const float x = fmaf(sf[g][e], C1, TblL[rh*TW + rw]);
                    pv[e] = v4 ? exp2f_(x) : 0.f;
                }
            } else {
#pragma unroll
                for (int e = 0; e < 4; ++e) {
                    int kk = kwi0 + e;
                    const int wrap = (kk >= GW);
                    kk -= wrap ? GW : 0;
                    const int kh2 = khi + wrap;
                    const int dh = qh - 4*kh2;
                    const int dw = qw - 4*kk;
                    const int rh = dh - 1 - (dh >= 2) + 23;
                    const int rw = dw - 1 - (dw >= 2) + (GW - 1);
                    const float x = fmaf(sf[g][e], C1, TblL[rh*TW + rw]);
                    pv[e] = v4 ? exp2f_(x) : 0.f;
                }
            }
            ls += (pv[0] + pv[1]) + (pv[2] + pv[3]);
            const unsigned int plo = (unsigned int)f2bf(pv[0]) | ((unsigned int)f2bf(pv[1]) << 16);
            const unsigned int phi = (unsigned int)f2bf(pv[2]) | ((unsigned int)f2bf(pv[3]) << 16);
            *(uint2*)&PlW[lr*72 + g*16 + kg*4] = make_uint2(plo, phi);
        }

        // out^T += V^T . P^T   (Pl same-wave write->read: DS in-order)
        __builtin_amdgcn_s_setprio(1);
#pragma unroll
        for (int ks = 0; ks < 2; ++ks) {
            const bf16x8 pb = *(const bf16x8*)&PlW[lr*72 + ks*32 + kg*8];
#pragma unroll
            for (int j = 0; j < 4; ++j) {
                const bf16x8 vb = *(const bf16x8*)&Vl[j*16 + lr][ks*32 + kg*8];
                pacc[j] = __builtin_amdgcn_mfma_f32_16x16x32_bf16(vb, pb, pacc[j], 0, 0, 0);
            }
        }
        __builtin_amdgcn_s_setprio(0);
    }

    // normalize and fold into octx
    ls += __shfl_xor(ls, 16);
    ls += __shfl_xor(ls, 32);
    const float inv = 1.0f / (3.0f * ls);
#pragma unroll
    for (int j = 0; j < 4; ++j)
#pragma unroll
        for (int e = 0; e < 4; ++e)
            octx[j][e] = fmaf(pacc[j][e], inv, octx[j][e]);
}

// ---------------------------------------------------------------------------
// Fused 3-scale attention. bid = qtile*192 + (b*12+h): q-tiles sharing one
// (b,h) K/V slice land on the same XCD (192 % 8 == 0) -> K/V L2-resident.
// ---------------------------------------------------------------------------
__global__ __launch_bounds__(256)
void attn_fused(const u16* __restrict__ Qbf,
                const u16* __restrict__ K1, const u16* __restrict__ V1t,
                const u16* __restrict__ K2, const u16* __restrict__ V2t,
                const u16* __restrict__ K4, const u16* __restrict__ V4t,
                const float* __restrict__ T1, const float* __restrict__ T2,
                const float* __restrict__ T4,
                u16* __restrict__ Ch, u16* __restrict__ Cl) {
    __shared__ u16 Kl[64][72];
    __shared__ u16 Vl[64][72];
    __shared__ u16 Pl[4][16][72];
    __shared__ float TblF[2209];
    const int tid  = threadIdx.x;
    const int wid  = tid >> 6;
    const int lane = tid & 63;
    const int lr   = lane & 15;
    const int kg   = lane >> 4;
    const int bid  = blockIdx.x;
    const int qt   = bid / 192;
    const int bh   = bid - qt*192;
    const int b    = bh / 12;
    const int h    = bh - b*12;
    const int qw0  = qt*64 + wid*16;
    const int q    = qw0 + lr;                 // this lane's q row
    const int qh   = q / 24, qw = q - qh*24;

    bf16x8 qa[2];
    {
        const u16* qp = Qbf + ((size_t)(b*T_) + q)*768 + h*64 + kg*8;
        qa[0] = *(const bf16x8*)qp;
        qa[1] = *(const bf16x8*)(qp + 32);
    }
    f32x4 octx[4];
#pragma unroll
    for (int j = 0; j < 4; ++j) octx[j] = (f32x4)(0.f);
    u16* PlW = &Pl[wid][0][0];

    attn_scale<576,24,1>(K1, V1t, T1, qa, qh, qw, b, h, tid, lr, kg, Kl, Vl, PlW, TblF, octx);
    attn_scale<144,12,2>(K2, V2t, T2, qa, qh, qw, b, h, tid, lr, kg, Kl, Vl, PlW, TblF, octx);
    attn_scale< 36, 6,4>(K4, V4t, T4, qa, qh, qw, b, h, tid, lr, kg, Kl, Vl, PlW, TblF, octx);

    // epilogue: packed ushort4 split-bf16 stores
    const size_t rowoff = ((size_t)(b*T_) + q)*768 + h*64;
#pragma unroll
    for (int j = 0; j < 4; ++j) {
        ushort4 hv, lv;
        u16 h0,h1,h2,h3, l0,l1,l2,l3;
        splitf(octx[j][0], h0, l0); splitf(octx[j][1], h1, l1);
        splitf(octx[j][2], h2, l2); splitf(octx[j][3], h3, l3);
        hv = make_ushort4(h0,h1,h2,h3); lv = make_ushort4(l0,l1,l2,l3);
        *(ushort4*)&Ch[rowoff + j*16 + kg*4] = hv;
        *(ushort4*)&Cl[rowoff + j*16 + kg*4] = lv;
    }
}

// ---------------------------------------------------------------------------
extern "C" void kernel_launch(void* const* d_in, const int* in_sizes, int n_in,
                              void* d_out, int out_size, void* d_ws, size_t ws_size,
                              hipStream_t stream) {
    const float* x    = (const float*)d_in[0];
    const float* wq   = (const float*)d_in[1];
    const float* wdkv = (const float*)d_in[2];
    const float* wuk1 = (const float*)d_in[3];
    const float* wuk2 = (const float*)d_in[4];
    const float* wuk4 = (const float*)d_in[5];
    const float* wuv1 = (const float*)d_in[6];
    const float* wuv2 = (const float*)d_in[7];
    const float* wuv4 = (const float*)d_in[8];
    const float* wout = (const float*)d_in[9];
    const float* bout = (const float*)d_in[10];
    const float* tbl1 = (const float*)d_in[11];
    const float* tbl2 = (const float*)d_in[12];
    const float* tbl4 = (const float*)d_in[13];

    u16* p = (u16*)d_ws;
    u16* x_bf   = p;            p += 7077888;
    u16* q_bf   = p;            p += 7077888;
    u16* lat_bf = p;            p += 2359296;
    u16* lp2_bf = p;            p += 589824;
    u16* lp4_bf = p;            p += 147456;
    u16* wqT    = p;            p += 589824;
    u16* wdkvT  = p;            p += 196608;
    u16* uk1T   = p;            p += 196608;
    u16* uv1T   = p;            p += 196608;
    u16* uk2T   = p;            p += 196608;
    u16* uv2T   = p;            p += 196608;
    u16* uk4T   = p;            p += 196608;
    u16* uv4T   = p;            p += 196608;
    u16* woutTh = p;            p += 589824;
    u16* woutTl = p;            p += 589824;
    u16* k1     = p;            p += 7077888;
    u16* v1t    = p;            p += 7077888;
    u16* k2     = p;            p += 1769472;
    u16* v2t    = p;            p += 1769472;
    u16* k4     = p;            p += 442368;
    u16* v4t    = p;            p += 442368;
    u16* ctxh   = p;            p += 7077888;
    u16* ctxl   = p;            p += 7077888;
    float* outp = (float*)d_out;

    // conversions / weight prep
    convert_bf<<<3456, 256, 0, stream>>>(x, x_bf, 7077888);
    prep_weights<<<2496, 256, 0, stream>>>(wq, wdkv, wuk1, wuv1, wuk2, wuv2,
                                           wuk4, wuv4, wout,
                                           wqT, wdkvT, uk1T, uv1T, uk2T, uv2T,
                                           uk4T, uv4T, woutTh, woutTl);

    // q + lat projections in one dual-N GEMM (N = 768 | 256)
    gemm_mfma<false,1,1,false><<<dim3(8,72), 256, 0, stream>>>(
        x_bf, nullptr, wqT, nullptr, wdkvT, nullptr, nullptr, q_bf, lat_bf,
        9216, 768, 256, 768, 0);
    pool_both<<<2880, 256, 0, stream>>>(lat_bf, lp2_bf, lp4_bf);

    // K|V up-projections, one dual-N GEMM per scale (N = 768 | 768)
    gemm_mfma<false,1,2,false><<<dim3(12,72), 256, 0, stream>>>(
        lat_bf, nullptr, uk1T, nullptr, uv1T, nullptr, nullptr, k1, v1t,
        9216, 768, 768, 256, 576);
    gemm_mfma<false,1,2,false><<<dim3(12,18), 256, 0, stream>>>(
        lp2_bf, nullptr, uk2T, nullptr, uv2T, nullptr, nullptr, k2, v2t,
        2304, 768, 768, 256, 144);
    gemm_mfma<false,1,2,false><<<dim3(12,5), 256, 0, stream>>>(
        lp4_bf, nullptr, uk4T, nullptr, uv4T, nullptr, nullptr, k4, v4t,
        576, 768, 768, 256, 36);

    // fused 3-scale attention
    attn_fused<<<9*192, 256, 0, stream>>>(q_bf, k1, v1t, k2, v2t, k4, v4t,
                                          tbl1, tbl2, tbl4, ctxh, ctxl);

    // output projection (split inputs for fp32-grade accuracy)
    gemm_mfma<true,0,-1,true><<<dim3(6,72), 256, 0, stream>>>(
        ctxh, ctxl, woutTh, woutTl, nullptr, bout, outp, nullptr, nullptr,
        9216, 768, 0, 768, 0);
}

// Round 7
// 293.285 us; speedup vs baseline: 4.8347x; 1.1285x over previous
//
#include <hip/hip_runtime.h>
#include <hip/hip_bf16.h>
#include <math.h>

#define B_   16
#define T_   576
#define NH_  12

typedef unsigned short u16;
typedef __attribute__((ext_vector_type(8))) short bf16x8;
typedef __attribute__((ext_vector_type(4))) float f32x4;

// ---------------------------------------------------------------------------
// helpers
// ---------------------------------------------------------------------------
__device__ __forceinline__ float bf2f(u16 u) {
    union { unsigned int i; float f; } x; x.i = ((unsigned int)u) << 16; return x.f;
}
__device__ __forceinline__ u16 f2bf(float f) {   // round-to-nearest-even
    union { float f; unsigned int i; } x; x.f = f;
    unsigned int r = x.i + 0x7fffu + ((x.i >> 16) & 1u);
    return (u16)(r >> 16);
}
__device__ __forceinline__ void splitf(float v, u16& h, u16& l) {
    h = f2bf(v);
    l = f2bf(v - bf2f(h));
}
__device__ __forceinline__ void gld_lds16(const u16* g, u16* l) {
    __builtin_amdgcn_global_load_lds(
        (const __attribute__((address_space(1))) unsigned int*)g,
        (__attribute__((address_space(3))) unsigned int*)l, 16, 0, 0);
}
__device__ __forceinline__ float exp2f_(float x) {
#if __has_builtin(__builtin_amdgcn_exp2f)
    return __builtin_amdgcn_exp2f(x);
#else
    return exp2f(x);
#endif
}

#define VMBAR() do { \
    asm volatile("s_waitcnt vmcnt(0)" ::: "memory"); \
    __builtin_amdgcn_s_barrier(); \
    __builtin_amdgcn_sched_barrier(0); } while (0)

// ---------------------------------------------------------------------------
// prep_all: blocks [0,3456) convert x to bf16; [3456,5952) weight transposes
// ---------------------------------------------------------------------------
__global__ __launch_bounds__(256)
void prep_all(const float* __restrict__ x, u16* __restrict__ x_bf,
              const float* __restrict__ wq, const float* __restrict__ wdkv,
              const float* __restrict__ uk1, const float* __restrict__ uv1,
              const float* __restrict__ uk2, const float* __restrict__ uv2,
              const float* __restrict__ uk4, const float* __restrict__ uv4,
              const float* __restrict__ wout,
              u16* wqT, u16* wdkvT, u16* uk1T, u16* uv1T, u16* uk2T,
              u16* uv2T, u16* uk4T, u16* uv4T, u16* woutTh, u16* woutTl) {
    __shared__ float t[32][33];
    int id = blockIdx.x;
    if (id < 3456) {
        const int i8 = (id * 256 + threadIdx.x) * 8;
        const float4 a = *(const float4*)&x[i8];
        const float4 b = *(const float4*)&x[i8 + 4];
        u16 o[8] = {f2bf(a.x),f2bf(a.y),f2bf(a.z),f2bf(a.w),
                    f2bf(b.x),f2bf(b.y),f2bf(b.z),f2bf(b.w)};
        *(bf16x8*)&x_bf[i8] = *(bf16x8*)o;
        return;
    }
    id -= 3456;
    const float* W; u16* Th; u16* Tl = nullptr; int K, N, gx; bool split = false;
    if (id < 576)       { W = wq;  Th = wqT;  K = 768; N = 768; gx = 24; }
    else if (id < 768)  { id -= 576; W = wdkv; Th = wdkvT; K = 768; N = 256; gx = 8; }
    else if (id < 1920) {
        id -= 768; const int w = id / 192; id -= w * 192;
        const float* Ws[6] = {uk1, uv1, uk2, uv2, uk4, uv4};
        u16* Ts[6] = {uk1T, uv1T, uk2T, uv2T, uk4T, uv4T};
        W = Ws[w]; Th = Ts[w]; K = 256; N = 768; gx = 24;
    } else { id -= 1920; W = wout; Th = woutTh; Tl = woutTl; K = 768; N = 768; gx = 24; split = true; }
    const int bx = id % gx, by = id / gx;
    const int n0 = bx * 32, k0 = by * 32;
    const int tid = threadIdx.x;
    const int c  = tid & 31;
    const int r4 = tid >> 5;
#pragma unroll
    for (int i = 0; i < 4; ++i)
        t[r4*4+i][c] = W[(size_t)(k0 + r4*4 + i) * N + n0 + c];
    __syncthreads();
#pragma unroll
    for (int i = 0; i < 4; ++i) {
        const float v = t[c][r4*4+i];
        const size_t o = (size_t)(n0 + r4*4 + i) * K + k0 + c;
        if (split) { u16 h, l; splitf(v, h, l); Th[o] = h; Tl[o] = l; }
        else       { Th[o] = f2bf(v); }
    }
}

// ---------------------------------------------------------------------------
// MFMA GEMM device body (shared by the generic global and kv_fused).
// B transposed [N][K]. 128x128 tile, BK=64, 4 waves.
// OM: 0 = fp32(+bias), 1 = bf16 [M][N], 2 = bf16 [b][N][KStS] (key=row%KStL)
// ---------------------------------------------------------------------------
template<bool IN_SPLIT, int OM1, int OM2, bool HAS_BIAS>
__device__ __forceinline__ void gemm_body(
               u16* smem, int bx, int by,
               const u16* __restrict__ Ah, const u16* __restrict__ Al,
               const u16* __restrict__ B1h, const u16* __restrict__ B1l,
               const u16* __restrict__ B2h,
               const float* __restrict__ bias, float* __restrict__ C1f,
               u16* __restrict__ C1bf, u16* __restrict__ C2bf,
               int M, int N1, int N2, int K, int KStL, int KStS) {
    const int tid  = threadIdx.x;
    const int wid  = tid >> 6;
    const int lane = tid & 63;
    const int lr   = lane & 15;
    const int kg   = lane >> 4;
    const int wr   = wid >> 1, wc = wid & 1;
    const int m0   = by * 128;
    const int n0   = bx * 128;
    const bool second = (OM2 >= 0) && (n0 >= N1);
    const int nb   = second ? n0 - N1 : n0;
    const int subrow = lane >> 3;
    const int gslot  = (lane & 7) ^ subrow;     // inverse swizzle on source

    const u16* src; int rowbase; bool isA; u16* tile;
    constexpr int NITER = IN_SPLIT ? 16 : 8;
    if (IN_SPLIT) {
        src = (wid == 0) ? Ah : (wid == 1) ? Al : (wid == 2) ? B1h : B1l;
        rowbase = (wid < 2) ? m0 : n0;
        isA = (wid < 2);
        tile = smem + wid * 8192;
    } else {
        const u16* Bsel = second ? B2h : B1h;
        src = (wid < 2) ? Ah : Bsel;
        rowbase = ((wid < 2) ? m0 : nb) + (wid & 1) * 64;
        isA = (wid < 2);
        tile = smem + (wid >> 1) * 8192 + (wid & 1) * 4096;
    }

    f32x4 acc[4][4];
#pragma unroll
    for (int i = 0; i < 4; ++i)
#pragma unroll
        for (int j = 0; j < 4; ++j) acc[i][j] = (f32x4)(0.f);

    for (int k0 = 0; k0 < K; k0 += 64) {
#pragma unroll
        for (int i = 0; i < NITER; ++i) {
            int grow = rowbase + i*8 + subrow;
            if (isA && grow >= M) grow = M - 1;   // clamp tail (dup loads ok)
            gld_lds16(src + (size_t)grow * K + (k0 + gslot * 8), tile + i * 512);
        }
        __syncthreads();
#pragma unroll
        for (int ks = 0; ks < 2; ++ks) {
            const int slot = (ks*4 + kg) ^ (lr & 7);
            bf16x8 ah[4], bh[4], al[4], bl[4];
#pragma unroll
            for (int i = 0; i < 4; ++i) {
                const int offA = (wr*64 + i*16 + lr) * 64 + slot * 8;
                const int offB = (wc*64 + i*16 + lr) * 64 + slot * 8;
                ah[i] = *(const bf16x8*)(smem + offA);
                bh[i] = *(const bf16x8*)(smem + (IN_SPLIT ? 16384 : 8192) + offB);
                if (IN_SPLIT) {
                    al[i] = *(const bf16x8*)(smem + 8192  + offA);
                    bl[i] = *(const bf16x8*)(smem + 24576 + offB);
                }
            }
#pragma unroll
            for (int i = 0; i < 4; ++i)
#pragma unroll
                for (int j = 0; j < 4; ++j) {
                    acc[i][j] = __builtin_amdgcn_mfma_f32_16x16x32_bf16(ah[i], bh[j], acc[i][j], 0, 0, 0);
                    if (IN_SPLIT) {
                        acc[i][j] = __builtin_amdgcn_mfma_f32_16x16x32_bf16(ah[i], bl[j], acc[i][j], 0, 0, 0);
                        acc[i][j] = __builtin_amdgcn_mfma_f32_16x16x32_bf16(al[i], bh[j], acc[i][j], 0, 0, 0);
                    }
                }
        }
        __syncthreads();
    }
    const int rb = lane >> 4;
    float bv[4];
    if (HAS_BIAS) {
#pragma unroll
        for (int j = 0; j < 4; ++j) bv[j] = bias[n0 + wc*64 + j*16 + lr];
    }
#pragma unroll
    for (int i = 0; i < 4; ++i)
#pragma unroll
        for (int e = 0; e < 4; ++e) {
            const int row = m0 + wr*64 + i*16 + rb*4 + e;
            if (row < M) {
#pragma unroll
                for (int j = 0; j < 4; ++j) {
                    const int colw = wc*64 + j*16 + lr;
                    float v = acc[i][j][e];
                    if (HAS_BIAS) v += bv[j];
                    if (!second) {
                        const int col = n0 + colw;
                        if (OM1 == 0) C1f[(size_t)row * N1 + col] = v;
                        else if (OM1 == 1) C1bf[(size_t)row * N1 + col] = f2bf(v);
                        else {
                            const int bidx = row / KStL, key = row - bidx * KStL;
                            C1bf[((size_t)bidx * N1 + col) * KStS + key] = f2bf(v);
                        }
                    } else {
                        const int col = nb + colw;
                        if (OM2 == 1) C2bf[(size_t)row * N2 + col] = f2bf(v);
                        else if (OM2 == 2) {
                            const int bidx = row / KStL, key = row - bidx * KStL;
                            C2bf[((size_t)bidx * N2 + col) * KStS + key] = f2bf(v);
                        }
                    }
                }
            }
        }
}

template<bool IN_SPLIT, int OM1, int OM2, bool HAS_BIAS>
__global__ __launch_bounds__(256, 2)
void gemm_mfma(const u16* __restrict__ Ah, const u16* __restrict__ Al,
               const u16* __restrict__ B1h, const u16* __restrict__ B1l,
               const u16* __restrict__ B2h,
               const float* __restrict__ bias, float* __restrict__ C1f,
               u16* __restrict__ C1bf, u16* __restrict__ C2bf,
               int M, int N1, int N2, int K, int KStL, int KStS) {
    __shared__ u16 smem[(IN_SPLIT ? 4 : 2) * 8192];
    gemm_body<IN_SPLIT,OM1,OM2,HAS_BIAS>(smem, blockIdx.x, blockIdx.y,
        Ah, Al, B1h, B1l, B2h, bias, C1f, C1bf, C2bf, M, N1, N2, K, KStL, KStS);
}

// All three K/V up-projection GEMMs in one launch.
__global__ __launch_bounds__(256, 2)
void kv_fused(const u16* __restrict__ lat, const u16* __restrict__ lp2,
              const u16* __restrict__ lp4,
              const u16* uk1T, const u16* uv1T, const u16* uk2T,
              const u16* uv2T, const u16* uk4T, const u16* uv4T,
              u16* k1, u16* v1t, u16* k2, u16* v2t, u16* k4, u16* v4t) {
    __shared__ u16 smem[2 * 8192];
    int bid = blockIdx.x;
    if (bid < 864) {
        gemm_body<false,1,2,false>(smem, bid % 12, bid / 12,
            lat, nullptr, uk1T, nullptr, uv1T, nullptr, nullptr, k1, v1t,
            9216, 768, 768, 256, 576, 576);
    } else if (bid < 1080) {
        bid -= 864;
        gemm_body<false,1,2,false>(smem, bid % 12, bid / 12,
            lp2, nullptr, uk2T, nullptr, uv2T, nullptr, nullptr, k2, v2t,
            2304, 768, 768, 256, 144, 144);
    } else {
        bid -= 1080;
        gemm_body<false,1,2,false>(smem, bid % 12, bid / 12,
            lp4, nullptr, uk4T, nullptr, uv4T, nullptr, nullptr, k4, v4t,
            576, 768, 768, 256, 36, 64);      // v4t padded to stride 64 (16B align)
    }
}

// ---------------------------------------------------------------------------
// Both mean pools from lat in one kernel. blocks [0,2304)=lp2, [2304,2880)=lp4
// ---------------------------------------------------------------------------
__global__ __launch_bounds__(256)
void pool_both(const u16* __restrict__ lat, u16* __restrict__ lp2,
               u16* __restrict__ lp4) {
    const int c = threadIdx.x;
    int id = blockIdx.x;
    if (id < 2304) {
        const int b = id / 144, g = id - b*144;
        const int gh = g / 12, gw = g - gh*12;
        const size_t i0 = (((size_t)(b*24 + gh*2))*24 + gw*2)*256 + c;
        const float s = (bf2f(lat[i0]) + bf2f(lat[i0+256]) +
                         bf2f(lat[i0+24*256]) + bf2f(lat[i0+24*256+256])) * 0.25f;
        lp2[(size_t)id*256 + c] = f2bf(s);
    } else {
        id -= 2304;
        const int b = id / 36, g = id - b*36;
        const int gh = g / 6, gw = g - gh*6;
        const size_t base = (((size_t)(b*24 + gh*4))*24 + gw*4)*256 + c;
        float s = 0.f;
#pragma unroll
        for (int i = 0; i < 4; ++i)
#pragma unroll
            for (int j = 0; j < 4; ++j)
                s += bf2f(lat[base + (size_t)(i*24 + j)*256]);
        lp4[(size_t)id*256 + c] = f2bf(s * (1.f/16.f));
    }
}

// ---------------------------------------------------------------------------
// Attention tile staging: global_load_lds into LINEAR [64 rows][64 cols] tile,
// source chunk pre-swizzled (chunk ^= row&7); reads use the same XOR.
// Each wave issues K slots {w,w+4} and V slots {w,w+4}: 4 gld_lds/wave/tile.
// ---------------------------------------------------------------------------
__device__ __forceinline__ void issue_tile(
    const u16* __restrict__ Kbf, const u16* __restrict__ Vt,
    int b, int h, int KS, int VSTR, int kt0,
    u16* Kdst, u16* Vdst, int wid, int lane)
{
    const int sub  = lane >> 3;                 // 0..7
    const int srcc = (lane & 7) ^ sub;          // source chunk swizzle
#pragma unroll
    for (int s = wid; s < 8; s += 4) {
        const int row = s*8 + sub;
        int gk = kt0 + row; gk = gk < KS ? gk : KS - 1;
        gld_lds16(Kbf + ((size_t)b*KS + gk)*768 + h*64 + srcc*8, Kdst + s*512);
    }
#pragma unroll
    for (int s = wid; s < 8; s += 4) {
        const int row = s*8 + sub;              // head dim
        gld_lds16(Vt + ((size_t)(b*768 + h*64 + row))*VSTR + kt0 + srcc*8,
                  Vdst + s*512);
    }
}

// ---------------------------------------------------------------------------
// One 64-key tile: QK (swapped operands), fixed-max log2 softmax, PV.
// Score layout: q = lr, keys = kt0 + g*16 + kg*4 + e.
// ---------------------------------------------------------------------------
template<int KS, int GW, int S>
__device__ __forceinline__ void attn_tile(
    int kt0, const u16* __restrict__ Kb, const u16* __restrict__ Vb,
    const float* __restrict__ TblL, u16* __restrict__ PlW,
    int qh, int qw, int base1, int lr, int kg,
    const bf16x8 qa[2], f32x4 pacc[4], float& ls)
{
    constexpr int TW = 2*GW - 1;
    constexpr float C1 = 0.18033688011112042f;   // 0.125 * log2(e)

    f32x4 sf[4];
#pragma unroll
    for (int g = 0; g < 4; ++g) sf[g] = (f32x4)(0.f);
    __builtin_amdgcn_s_setprio(1);
#pragma unroll
    for (int ks = 0; ks < 2; ++ks)
#pragma unroll
        for (int g = 0; g < 4; ++g) {
            const int rc = (ks*4 + kg) ^ (lr & 7);
            const bf16x8 kb = *(const bf16x8*)(Kb + (g*16 + lr)*64 + rc*8);
            sf[g] = __builtin_amdgcn_mfma_f32_16x16x32_bf16(kb, qa[ks], sf[g], 0, 0, 0);
        }
    __builtin_amdgcn_s_setprio(0);

#pragma unroll
    for (int g = 0; g < 4; ++g) {
        const int key0 = kt0 + g*16 + kg*4;
        const bool v4 = ((KS % 64) == 0) || (key0 < KS);
        float pv[4];
        if (v4) {
            const int khi  = key0 / GW;
            const int kwi0 = key0 - khi*GW;
            if (S == 1) {
                const int idx0 = base1 - khi*TW - kwi0;
#pragma unroll
                for (int e = 0; e < 4; ++e)
                    pv[e] = exp2f_(fmaf(sf[g][e], C1, TblL[idx0 - e]));
            } else if (S == 2) {
                const int dh = qh - 2*khi;
                const int rh = dh - (dh >= 1) + 23;
#pragma unroll
                for (int e = 0; e < 4; ++e) {
                    const int dw = qw - 2*(kwi0 + e);
                    const int rw = dw - (dw >= 1) + (GW - 1);
                    pv[e] = exp2f_(fmaf(sf[g][e], C1, TblL[rh*TW + rw]));
                }
            } else {
#pragma unroll
                for (int e = 0; e < 4; ++e) {
                    int kk = kwi0 + e;
                    const int wrap = (kk >= GW);
                    kk -= wrap ? GW : 0;
                    const int kh2 = khi + wrap;
                    const int dh = qh - 4*kh2;
                    const int dw = qw - 4*kk;
                    const int rh = dh - 1 - (dh >= 2) + 23;
                    const int rw = dw - 1 - (dw >= 2) + (GW - 1);
                    pv[e] = exp2f_(fmaf(sf[g][e], C1, TblL[rh*TW + rw]));
                }
            }
        } else {
            pv[0] = pv[1] = pv[2] = pv[3] = 0.f;
        }
        ls += (pv[0] + pv[1]) + (pv[2] + pv[3]);
        const unsigned int plo = (unsigned int)f2bf(pv[0]) | ((unsigned int)f2bf(pv[1]) << 16);
        const unsigned int phi = (unsigned int)f2bf(pv[2]) | ((unsigned int)f2bf(pv[3]) << 16);
        *(uint2*)&PlW[lr*72 + g*16 + kg*4] = make_uint2(plo, phi);
    }

    // out^T += V^T . P^T  (Pl same-wave write->read: DS in-order)
    __builtin_amdgcn_s_setprio(1);
#pragma unroll
    for (int ks = 0; ks < 2; ++ks) {
        const bf16x8 pb = *(const bf16x8*)(PlW + lr*72 + ks*32 + kg*8);
#pragma unroll
        for (int j = 0; j < 4; ++j) {
            const int rc = (ks*4 + kg) ^ (lr & 7);
            const bf16x8 vb = *(const bf16x8*)(Vb + (j*16 + lr)*64 + rc*8);
            pacc[j] = __builtin_amdgcn_mfma_f32_16x16x32_bf16(vb, pb, pacc[j], 0, 0, 0);
        }
    }
    __builtin_amdgcn_s_setprio(0);
}

__device__ __forceinline__ void fold3(f32x4 pacc[4], float& ls, f32x4 octx[4]) {
    float l = ls;
    l += __shfl_xor(l, 16);
    l += __shfl_xor(l, 32);
    const float inv = 1.0f / (3.0f * l);
#pragma unroll
    for (int j = 0; j < 4; ++j) {
#pragma unroll
        for (int e = 0; e < 4; ++e)
            octx[j][e] = fmaf(pacc[j][e], inv, octx[j][e]);
        pacc[j] = (f32x4)(0.f);
    }
    ls = 0.f;
}

// ---------------------------------------------------------------------------
// Fused 3-scale attention, software-pipelined: double-buffered K/V LDS tiles,
// raw s_barrier + counted vmcnt (one barrier per tile), prefetch across scale
// boundaries. bid = qtile*192 + (b*12+h) keeps (b,h) K/V on one XCD.
// ---------------------------------------------------------------------------
__global__ __launch_bounds__(256)
void attn_fused(const u16* __restrict__ Qbf,
                const u16* __restrict__ K1, const u16* __restrict__ V1t,
                const u16* __restrict__ K2, const u16* __restrict__ V2t,
                const u16* __restrict__ K4, const u16* __restrict__ V4t,
                const float* __restrict__ T1, const float* __restrict__ T2,
                const float* __restrict__ T4,
                u16* __restrict__ Ch, u16* __restrict__ Cl) {
    __shared__ u16 KlA[4096], KlB[4096], VlA[4096], VlB[4096];
    __shared__ u16 Pl[4][16*72];
    __shared__ float Tb[3807];          // [0)=s1 2209, [2209)=s2 1081, [3290)=s4 517
    const int tid  = threadIdx.x;
    const int wid  = tid >> 6;
    const int lane = tid & 63;
    const int lr   = lane & 15;
    const int kg   = lane >> 4;
    const int bid  = blockIdx.x;
    const int qt   = bid / 192;
    const int bh   = bid - qt*192;
    const int b    = bh / 12;
    const int h    = bh - b*12;
    const int qw0  = qt*64 + wid*16;
    const int q    = qw0 + lr;
    const int qh   = q / 24, qw = q - qh*24;
    const int base1 = (qh + 23)*47 + qw + 23;
    constexpr float LOG2E = 1.4426950408889634f;

    // prologue: issue tile0 loads, stage all 3 bias tables, drain, barrier
    issue_tile(K1, V1t, b, h, 576, 576, 0, KlA, VlA, wid, lane);
    for (int i = tid; i < 2209; i += 256) Tb[i]        = T1[(size_t)h*2209 + i] * LOG2E;
    for (int i = tid; i < 1081; i += 256) Tb[2209 + i] = T2[(size_t)h*1081 + i] * LOG2E;
    for (int i = tid; i < 517;  i += 256) Tb[3290 + i] = T4[(size_t)h*517  + i] * LOG2E;
    asm volatile("s_waitcnt vmcnt(0) lgkmcnt(0)" ::: "memory");
    __builtin_amdgcn_s_barrier();
    __builtin_amdgcn_sched_barrier(0);

    bf16x8 qa[2];
    {
        const u16* qp = Qbf + ((size_t)(b*T_) + q)*768 + h*64 + kg*8;
        qa[0] = *(const bf16x8*)qp;
        qa[1] = *(const bf16x8*)(qp + 32);
    }
    f32x4 octx[4], pacc[4];
#pragma unroll
    for (int j = 0; j < 4; ++j) { octx[j] = (f32x4)(0.f); pacc[j] = (f32x4)(0.f); }
    float ls = 0.f;
    u16* PlW = &Pl[wid][0];

    // ---- scale 1: tiles 0..8 (tile t in buf (t&1?B:A)) ----
#pragma unroll 2
    for (int t = 0; t < 8; ++t) {
        issue_tile(K1, V1t, b, h, 576, 576, (t+1)*64,
                   (t&1) ? KlA : KlB, (t&1) ? VlA : VlB, wid, lane);
        attn_tile<576,24,1>(t*64, (t&1) ? KlB : KlA, (t&1) ? VlB : VlA,
                            Tb, PlW, qh, qw, base1, lr, kg, qa, pacc, ls);
        VMBAR();
    }
    issue_tile(K2, V2t, b, h, 144, 144, 0, KlB, VlB, wid, lane);      // t=8: cur A
    attn_tile<576,24,1>(512, KlA, VlA, Tb, PlW, qh, qw, base1, lr, kg, qa, pacc, ls);
    VMBAR();
    fold3(pacc, ls, octx);

    // ---- scale 2: tiles in B, A, B ----
    issue_tile(K2, V2t, b, h, 144, 144, 64, KlA, VlA, wid, lane);
    attn_tile<144,12,2>(0, KlB, VlB, Tb + 2209, PlW, qh, qw, 0, lr, kg, qa, pacc, ls);
    VMBAR();
    issue_tile(K2, V2t, b, h, 144, 144, 128, KlB, VlB, wid, lane);
    attn_tile<144,12,2>(64, KlA, VlA, Tb + 2209, PlW, qh, qw, 0, lr, kg, qa, pacc, ls);
    VMBAR();
    issue_tile(K4, V4t, b, h, 36, 64, 0, KlA, VlA, wid, lane);
    attn_tile<144,12,2>(128, KlB, VlB, Tb + 2209, PlW, qh, qw, 0, lr, kg, qa, pacc, ls);
    VMBAR();
    fold3(pacc, ls, octx);

    // ---- scale 4: one tile in A ----
    attn_tile<36,6,4>(0, KlA, VlA, Tb + 3290, PlW, qh, qw, 0, lr, kg, qa, pacc, ls);
    fold3(pacc, ls, octx);

    // epilogue: packed ushort4 split-bf16 stores
    const size_t rowoff = ((size_t)(b*T_) + q)*768 + h*64;
#pragma unroll
    for (int j = 0; j < 4; ++j) {
        u16 h0,h1,h2,h3, l0,l1,l2,l3;
        splitf(octx[j][0], h0, l0); splitf(octx[j][1], h1, l1);
        splitf(octx[j][2], h2, l2); splitf(octx[j][3], h3, l3);
        *(ushort4*)&Ch[rowoff + j*16 + kg*4] = make_ushort4(h0,h1,h2,h3);
        *(ushort4*)&Cl[rowoff + j*16 + kg*4] = make_ushort4(l0,l1,l2,l3);
    }
}

// ---------------------------------------------------------------------------
extern "C" void kernel_launch(void* const* d_in, const int* in_sizes, int n_in,
                              void* d_out, int out_size, void* d_ws, size_t ws_size,
                              hipStream_t stream) {
    const float* x    = (const float*)d_in[0];
    const float* wq   = (const float*)d_in[1];
    const float* wdkv = (const float*)d_in[2];
    const float* wuk1 = (const float*)d_in[3];
    const float* wuk2 = (const float*)d_in[4];
    const float* wuk4 = (const float*)d_in[5];
    const float* wuv1 = (const float*)d_in[6];
    const float* wuv2 = (const float*)d_in[7];
    const float* wuv4 = (const float*)d_in[8];
    const float* wout = (const float*)d_in[9];
    const float* bout = (const float*)d_in[10];
    const float* tbl1 = (const float*)d_in[11];
    const float* tbl2 = (const float*)d_in[12];
    const float* tbl4 = (const float*)d_in[13];

    u16* p = (u16*)d_ws;
    u16* x_bf   = p;            p += 7077888;
    u16* q_bf   = p;            p += 7077888;
    u16* lat_bf = p;            p += 2359296;
    u16* lp2_bf = p;            p += 589824;
    u16* lp4_bf = p;            p += 147456;
    u16* wqT    = p;            p += 589824;
    u16* wdkvT  = p;            p += 196608;
    u16* uk1T   = p;            p += 196608;
    u16* uv1T   = p;            p += 196608;
    u16* uk2T   = p;            p += 196608;
    u16* uv2T   = p;            p += 196608;
    u16* uk4T   = p;            p += 196608;
    u16* uv4T   = p;            p += 196608;
    u16* woutTh = p;            p += 589824;
    u16* woutTl = p;            p += 589824;
    u16* k1     = p;            p += 7077888;
    u16* v1t    = p;            p += 7077888;
    u16* k2     = p;            p += 1769472;
    u16* v2t    = p;            p += 1769472;
    u16* k4     = p;            p += 442368;
    u16* v4t    = p;            p += 786432;   // stride-64 padded
    u16* ctxh   = p;            p += 7077888;
    u16* ctxl   = p;            p += 7077888;
    float* outp = (float*)d_out;

    // conversions + weight prep (one kernel)
    prep_all<<<5952, 256, 0, stream>>>(x, x_bf, wq, wdkv, wuk1, wuv1, wuk2,
                                       wuv2, wuk4, wuv4, wout,
                                       wqT, wdkvT, uk1T, uv1T, uk2T, uv2T,
                                       uk4T, uv4T, woutTh, woutTl);

    // q + lat projections in one dual-N GEMM (N = 768 | 256)
    gemm_mfma<false,1,1,false><<<dim3(8,72), 256, 0, stream>>>(
        x_bf, nullptr, wqT, nullptr, wdkvT, nullptr, nullptr, q_bf, lat_bf,
        9216, 768, 256, 768, 0, 0);
    pool_both<<<2880, 256, 0, stream>>>(lat_bf, lp2_bf, lp4_bf);

    // all K|V up-projections in one launch
    kv_fused<<<1140, 256, 0, stream>>>(lat_bf, lp2_bf, lp4_bf,
                                       uk1T, uv1T, uk2T, uv2T, uk4T, uv4T,
                                       k1, v1t, k2, v2t, k4, v4t);

    // fused, pipelined 3-scale attention
    attn_fused<<<9*192, 256, 0, stream>>>(q_bf, k1, v1t, k2, v2t, k4, v4t,
                                          tbl1, tbl2, tbl4, ctxh, ctxl);

    // output projection (split inputs for fp32-grade accuracy)
    gemm_mfma<true,0,-1,true><<<dim3(6,72), 256, 0, stream>>>(
        ctxh, ctxl, woutTh, woutTl, nullptr, bout, outp, nullptr, nullptr,
        9216, 768, 0, 768, 0, 0);
}